// Round 10
// baseline (332.093 us; speedup 1.0000x reference)
//
#include <hip/hip_runtime.h>
#include <hip/hip_bf16.h>
#include <math.h>

#define N_NODES 50000
#define N_EDGES 800000
#define IN_DIM 128
#define HID 64
#define HEADS 4
#define MEGA_NB 512

typedef unsigned short ushort_t;
typedef __attribute__((ext_vector_type(8))) short bf16x8;
typedef __attribute__((ext_vector_type(4))) float f32x4;

static __device__ __forceinline__ ushort_t f2bf(float f) {
  __hip_bfloat16 b = __float2bfloat16(f);
  return *(ushort_t*)&b;
}
static __device__ __forceinline__ float bflo(unsigned d) {
  union { unsigned u; float f; } c; c.u = d << 16; return c.f;
}
static __device__ __forceinline__ float bfhi(unsigned d) {
  union { unsigned u; float f; } c; c.u = d & 0xffff0000u; return c.f;
}
static __device__ __forceinline__ unsigned packbf(float lo, float hi) {
  return (unsigned)f2bf(lo) | ((unsigned)f2bf(hi) << 16);
}
static __device__ __forceinline__ float lrelu(float x) {
  return (x > 0.f) ? x : 0.01f * x;
}

// grid-wide barrier: all blocks co-resident (512 blocks, 2/CU guaranteed).
static __device__ __forceinline__ void grid_barrier(unsigned* bar, unsigned nb) {
  __syncthreads();
  if (threadIdx.x == 0) {
    __threadfence();  // release: flush this block's writes device-wide
    __hip_atomic_fetch_add(bar, 1u, __ATOMIC_ACQ_REL, __HIP_MEMORY_SCOPE_AGENT);
    while (__hip_atomic_load(bar, __ATOMIC_ACQUIRE, __HIP_MEMORY_SCOPE_AGENT) < nb)
      __builtin_amdgcn_s_sleep(8);
    __threadfence();  // acquire: invalidate stale L2 before reading others' data
  }
  __syncthreads();
}

// ============ mega kernel: pack+hist | scan | place + gemm1 + off ============
// P0: pack W1/W2 into MFMA B-frag layout (24 units) + dst histogram (3125)
// P1: per-1024-node block scans (49 units)
// P2: place (3125) + gemm1 32-row tiles (1563) + off-finalize (49)
__global__ __launch_bounds__(256, 2) void k_mega(
    const float* __restrict__ w1, const float* __restrict__ w2,
    ushort_t* __restrict__ bpk1, ushort_t* __restrict__ bpk2,
    const int* __restrict__ dst, const int* __restrict__ src,
    int* __restrict__ cnt, int* __restrict__ cnt2, unsigned* __restrict__ bar,
    int* __restrict__ offp, int* __restrict__ bsum, int* __restrict__ off,
    int* __restrict__ ssrc,
    const float* __restrict__ A, ushort_t* __restrict__ C,
    const float* __restrict__ al, const float* __restrict__ ar,
    float* __restrict__ el, float* __restrict__ er) {
  __shared__ char smraw[2816];  // [0,2560): As[32][40] / scan[256]; [2560,2816): pref
  const int tid = threadIdx.x;
  const unsigned nb = gridDim.x;

  // ---------------- P0: weight pack + histogram ----------------
  for (int u = blockIdx.x; u < 24 + 3125; u += MEGA_NB) {
    if (u < 24) {
      int t = u * 256 + tid;
      if (t < 4096) {
        int l = t & 63, rem = t >> 6;
        int kk = rem & 3, ct = (rem >> 2) & 3, hh = rem >> 4;
        int kb = kk * 32 + (l >> 4) * 8;
        int col = hh * 64 + ct * 16 + (l & 15);
        ushort_t v[8];
        #pragma unroll
        for (int j = 0; j < 8; ++j) v[j] = f2bf(w1[(kb + j) * 256 + col]);
        *(uint4*)&bpk1[t * 8] = *(uint4*)v;
      } else {
        int q = t - 4096;
        int l = q & 63, rem = q >> 6;
        int kk = rem & 7, ct = rem >> 3;
        int kb = kk * 32 + (l >> 4) * 8;
        int col = ct * 16 + (l & 15);
        ushort_t v[8];
        #pragma unroll
        for (int j = 0; j < 8; ++j) v[j] = f2bf(w2[(kb + j) * 64 + col]);
        *(uint4*)&bpk2[q * 8] = *(uint4*)v;
      }
    } else {
      int e = (u - 24) * 256 + tid;
      if (e < N_EDGES) atomicAdd(&cnt[dst[e]], 1);
    }
  }
  grid_barrier(&bar[0], nb);

  // ---------------- P1: per-block scan (49 units x 1024 nodes) ----------------
  for (int u = blockIdx.x; u < 49; u += MEGA_NB) {
    int* lds = (int*)smraw;
    int i = u * 1024 + tid * 4;
    int v0 = 0, v1 = 0, v2 = 0, v3 = 0;
    if (i + 3 < N_NODES) {
      int4 q = *(const int4*)&cnt[i];
      v0 = q.x; v1 = q.y; v2 = q.z; v3 = q.w;
    } else {
      if (i < N_NODES) v0 = cnt[i];
      if (i + 1 < N_NODES) v1 = cnt[i + 1];
      if (i + 2 < N_NODES) v2 = cnt[i + 2];
      if (i + 3 < N_NODES) v3 = cnt[i + 3];
    }
    int t = v0 + v1 + v2 + v3;
    lds[tid] = t;
    __syncthreads();
    for (int s = 1; s < 256; s <<= 1) {
      int u2 = (tid >= s) ? lds[tid - s] : 0;
      __syncthreads();
      lds[tid] += u2;
      __syncthreads();
    }
    int excl = lds[tid] - t;
    if (i < N_NODES) offp[i] = excl;
    if (i + 1 < N_NODES) offp[i + 1] = excl + v0;
    if (i + 2 < N_NODES) offp[i + 2] = excl + v0 + v1;
    if (i + 3 < N_NODES) offp[i + 3] = excl + v0 + v1 + v2;
    if (tid == 255) bsum[u] = lds[255];
    __syncthreads();
  }
  grid_barrier(&bar[1], nb);

  // pref: exclusive prefix of bsum[49] (once per block)
  int* pref = (int*)(smraw + 2560);
  if (tid < 64) {
    int v = (tid < 49) ? bsum[tid] : 0;
    int orig = v;
    #pragma unroll
    for (int o = 1; o < 64; o <<= 1) { int t2 = __shfl_up(v, o); if (tid >= o) v += t2; }
    pref[tid] = v - orig;
  }
  __syncthreads();

  // ---------------- P2: place (3125) + gemm1 (1563) + off-fin (49) ------------
  ushort_t (*As)[40] = (ushort_t(*)[40])smraw;
  for (int u = blockIdx.x; u < 3125 + 1563 + 49; u += MEGA_NB) {
    if (u < 3125) {
      int e = u * 256 + tid;
      if (e < N_EDGES) {
        int d = dst[e];
        int p = atomicAdd(&cnt2[d], 1);
        ssrc[offp[d] + pref[d >> 10] + p] = src[e];
      }
    } else if (u < 3125 + 1563) {
      // gemm1 unit: rows [m0, m0+32) x all 256 cols; wave = head
      int m0 = (u - 3125) * 32;
      const int w = tid >> 6, l = tid & 63;
      const int lr = l & 15, lk = l >> 4;
      f32x4 acc[2][4] = {};
      #pragma unroll
      for (int kk = 0; kk < 4; ++kk) {
        {
          int r = tid >> 3, kc = (tid & 7) * 4;
          float4 v = make_float4(0.f, 0.f, 0.f, 0.f);
          if (m0 + r < N_NODES) v = *(const float4*)&A[(size_t)(m0 + r) * IN_DIM + kk * 32 + kc];
          *(uint2*)&As[r][kc] = make_uint2(packbf(v.x, v.y), packbf(v.z, v.w));
        }
        __syncthreads();
        bf16x8 a0 = *(const bf16x8*)&As[lr][lk * 8];
        bf16x8 a1 = *(const bf16x8*)&As[16 + lr][lk * 8];
        #pragma unroll
        for (int ct = 0; ct < 4; ++ct) {
          bf16x8 b = ((const bf16x8*)bpk1)[((w * 4 + ct) * 4 + kk) * 64 + l];
          acc[0][ct] = __builtin_amdgcn_mfma_f32_16x16x32_bf16(a0, b, acc[0][ct], 0, 0, 0);
          acc[1][ct] = __builtin_amdgcn_mfma_f32_16x16x32_bf16(a1, b, acc[1][ct], 0, 0, 0);
        }
        __syncthreads();
      }
      float ala[4], ara[4];
      #pragma unroll
      for (int ct = 0; ct < 4; ++ct) {
        ala[ct] = al[w * 64 + ct * 16 + lr];
        ara[ct] = ar[w * 64 + ct * 16 + lr];
      }
      #pragma unroll
      for (int rt = 0; rt < 2; ++rt)
        #pragma unroll
        for (int j = 0; j < 4; ++j) {
          float pel = 0.f, per = 0.f;
          #pragma unroll
          for (int ct = 0; ct < 4; ++ct) {
            float v = acc[rt][ct][j];
            pel = fmaf(v, ala[ct], pel);
            per = fmaf(v, ara[ct], per);
          }
          #pragma unroll
          for (int o = 1; o <= 8; o <<= 1) {
            pel += __shfl_xor(pel, o);
            per += __shfl_xor(per, o);
          }
          int row = m0 + rt * 16 + lk * 4 + j;
          if (lr == 0 && row < N_NODES) { el[row * 4 + w] = pel; er[row * 4 + w] = per; }
        }
      #pragma unroll
      for (int rt = 0; rt < 2; ++rt)
        #pragma unroll
        for (int ct = 0; ct < 4; ++ct)
          #pragma unroll
          for (int j = 0; j < 4; ++j) {
            int row = m0 + rt * 16 + lk * 4 + j;
            if (row < N_NODES)
              C[(size_t)row * 256 + w * 64 + ct * 16 + lr] = f2bf(acc[rt][ct][j]);
          }
    } else {
      int b2 = u - (3125 + 1563);
      int e0 = pref[b2];
      int i = b2 * 1024 + tid * 4;
      if (i + 3 < N_NODES) {
        int4 q = *(const int4*)&offp[i];
        *(int4*)&off[i] = make_int4(q.x + e0, q.y + e0, q.z + e0, q.w + e0);
      } else {
        if (i < N_NODES) off[i] = offp[i] + e0;
        if (i + 1 < N_NODES) off[i + 1] = offp[i + 1] + e0;
        if (i + 2 < N_NODES) off[i + 2] = offp[i + 2] + e0;
        if (i + 3 < N_NODES) off[i + 3] = offp[i + 3] + e0;
      }
      if (b2 == 0 && tid == 0) off[N_NODES] = N_EDGES;
    }
    __syncthreads();
  }
}

// ==== layer-1 agg, fused softmax (unchanged from R8) ====
__global__ __launch_bounds__(256) void agg4f_k(const ushort_t* __restrict__ ftb,
                                               const float* __restrict__ el,
                                               const float* __restrict__ er,
                                               const int* __restrict__ off,
                                               const int* __restrict__ ssrc,
                                               const float* __restrict__ bias,
                                               ushort_t* __restrict__ outb) {
  __shared__ float wl[4][64][4];
  __shared__ int srcl[4][64];
  int wv = threadIdx.x >> 6, lane = threadIdx.x & 63;
  int n = blockIdx.x * 4 + wv;
  if (n >= N_NODES) return;
  int s0 = off[n], s1 = off[n + 1];
  int half = lane >> 5, sl = lane & 31;
  int head = sl >> 3;
  const float4* el4 = (const float4*)el;
  float4 erv = ((const float4*)er)[n];
  float4 sum = make_float4(0.f, 0.f, 0.f, 0.f);
  float acc[8] = {};
  for (int c = s0; c < s1; c += 64) {
    int e = c + lane;
    float4 ex = make_float4(0.f, 0.f, 0.f, 0.f);
    int s = 0;
    if (e < s1) {
      s = ssrc[e];
      float4 q = el4[s];
      ex.x = __expf(lrelu(q.x + erv.x));
      ex.y = __expf(lrelu(q.y + erv.y));
      ex.z = __expf(lrelu(q.z + erv.z));
      ex.w = __expf(lrelu(q.w + erv.w));
      sum.x += ex.x; sum.y += ex.y; sum.z += ex.z; sum.w += ex.w;
    }
    srcl[wv][lane] = s;
    *(float4*)&wl[wv][lane][0] = ex;
    int cend = (c + 64 < s1) ? c + 64 : s1;
    #pragma unroll 4
    for (int i = c; i < cend; i += 2) {
      int e2 = i + half;
      if (e2 < cend) {
        int idx = e2 - c;
        int ss = srcl[wv][idx];
        float w = wl[wv][idx][head];
        uint4 u = *(const uint4*)&ftb[ss * 256 + sl * 8];
        acc[0] = fmaf(w, bflo(u.x), acc[0]);
        acc[1] = fmaf(w, bfhi(u.x), acc[1]);
        acc[2] = fmaf(w, bflo(u.y), acc[2]);
        acc[3] = fmaf(w, bfhi(u.y), acc[3]);
        acc[4] = fmaf(w, bflo(u.z), acc[4]);
        acc[5] = fmaf(w, bfhi(u.z), acc[5]);
        acc[6] = fmaf(w, bflo(u.w), acc[6]);
        acc[7] = fmaf(w, bfhi(u.w), acc[7]);
      }
    }
  }
  #pragma unroll
  for (int o = 1; o <= 32; o <<= 1) {
    sum.x += __shfl_xor(sum.x, o); sum.y += __shfl_xor(sum.y, o);
    sum.z += __shfl_xor(sum.z, o); sum.w += __shfl_xor(sum.w, o);
  }
  #pragma unroll
  for (int j = 0; j < 8; ++j) acc[j] += __shfl_xor(acc[j], 32);
  if (half == 0) {
    float sd = (head == 0) ? sum.x : (head == 1) ? sum.y : (head == 2) ? sum.z : sum.w;
    float rsv = (s1 > s0) ? 1.f / sd : 0.f;
    float4 b0 = ((const float4*)bias)[sl * 2];
    float4 b1 = ((const float4*)bias)[sl * 2 + 1];
    float o[8] = {fmaf(acc[0], rsv, b0.x), fmaf(acc[1], rsv, b0.y),
                  fmaf(acc[2], rsv, b0.z), fmaf(acc[3], rsv, b0.w),
                  fmaf(acc[4], rsv, b1.x), fmaf(acc[5], rsv, b1.y),
                  fmaf(acc[6], rsv, b1.z), fmaf(acc[7], rsv, b1.w)};
    #pragma unroll
    for (int j = 0; j < 8; ++j) o[j] = (o[j] > 0.f) ? o[j] : expm1f(o[j]);
    uint4 p;
    p.x = packbf(o[0], o[1]); p.y = packbf(o[2], o[3]);
    p.z = packbf(o[4], o[5]); p.w = packbf(o[6], o[7]);
    *(uint4*)&outb[n * 256 + sl * 8] = p;
  }
}

// ==== layer-2 GEMM (unchanged from R8) ====
__global__ __launch_bounds__(512) void gemm2_mfma(const ushort_t* __restrict__ A,
                                                  const ushort_t* __restrict__ Bpk,
                                                  ushort_t* __restrict__ C,
                                                  const float* __restrict__ al,
                                                  const float* __restrict__ ar,
                                                  float* __restrict__ el,
                                                  float* __restrict__ er, int M) {
  __shared__ ushort_t As[128][40];
  const int tid = threadIdx.x;
  const int m0 = blockIdx.x * 128;
  const int w = tid >> 6, l = tid & 63;
  const int lr = l & 15, lk = l >> 4;
  f32x4 acc[4] = {};

  #pragma unroll
  for (int kk = 0; kk < 8; ++kk) {
    int k0 = kk * 32;
    {
      int r = tid >> 2, kc = (tid & 3) * 8;
      uint4 v = make_uint4(0, 0, 0, 0);
      if (m0 + r < M) v = *(const uint4*)&A[(size_t)(m0 + r) * 256 + k0 + kc];
      *(uint4*)&As[r][kc] = v;
    }
    __syncthreads();
    bf16x8 a = *(const bf16x8*)&As[w * 16 + lr][lk * 8];
    #pragma unroll
    for (int ct = 0; ct < 4; ++ct) {
      bf16x8 b = ((const bf16x8*)Bpk)[(ct * 8 + kk) * 64 + l];
      acc[ct] = __builtin_amdgcn_mfma_f32_16x16x32_bf16(a, b, acc[ct], 0, 0, 0);
    }
    __syncthreads();
  }
  float ala[4], ara[4];
  #pragma unroll
  for (int ct = 0; ct < 4; ++ct) {
    ala[ct] = al[ct * 16 + lr];
    ara[ct] = ar[ct * 16 + lr];
  }
  #pragma unroll
  for (int j = 0; j < 4; ++j) {
    float pel = 0.f, per = 0.f;
    #pragma unroll
    for (int ct = 0; ct < 4; ++ct) {
      float v = acc[ct][j];
      pel = fmaf(v, ala[ct], pel);
      per = fmaf(v, ara[ct], per);
    }
    #pragma unroll
    for (int o = 1; o <= 8; o <<= 1) {
      pel += __shfl_xor(pel, o);
      per += __shfl_xor(per, o);
    }
    int row = m0 + w * 16 + lk * 4 + j;
    if (lr == 0 && row < M) { el[row] = pel; er[row] = per; }
  }
  #pragma unroll
  for (int ct = 0; ct < 4; ++ct)
    #pragma unroll
    for (int j = 0; j < 4; ++j) {
      int row = m0 + w * 16 + lk * 4 + j;
      if (row < M) C[(size_t)row * 64 + ct * 16 + lr] = f2bf(acc[ct][j]);
    }
}

// ==== layer-2 agg, fused softmax (unchanged from R8) ====
__global__ __launch_bounds__(256) void agg1f_k(const ushort_t* __restrict__ ftb,
                                               const float* __restrict__ el,
                                               const float* __restrict__ er,
                                               const int* __restrict__ off,
                                               const int* __restrict__ ssrc,
                                               const float* __restrict__ bias,
                                               float* __restrict__ out) {
  __shared__ float wl[4][64];
  __shared__ int srcl[4][64];
  int wv = threadIdx.x >> 6, lane = threadIdx.x & 63;
  int n = blockIdx.x * 4 + wv;
  if (n >= N_NODES) return;
  int s0 = off[n], s1 = off[n + 1];
  int g = lane >> 3, cg = lane & 7;
  float erv = er[n];
  float sum = 0.f;
  float acc[8] = {};
  for (int c = s0; c < s1; c += 64) {
    int e = c + lane;
    float ex = 0.f;
    int s = 0;
    if (e < s1) {
      s = ssrc[e];
      ex = __expf(lrelu(el[s] + erv));
      sum += ex;
    }
    srcl[wv][lane] = s;
    wl[wv][lane] = ex;
    int cend = (c + 64 < s1) ? c + 64 : s1;
    #pragma unroll 2
    for (int i = c; i < cend; i += 8) {
      int e2 = i + g;
      if (e2 < cend) {
        int idx = e2 - c;
        int ss = srcl[wv][idx];
        float w = wl[wv][idx];
        uint4 u = *(const uint4*)&ftb[ss * 64 + cg * 8];
        acc[0] = fmaf(w, bflo(u.x), acc[0]);
        acc[1] = fmaf(w, bfhi(u.x), acc[1]);
        acc[2] = fmaf(w, bflo(u.y), acc[2]);
        acc[3] = fmaf(w, bfhi(u.y), acc[3]);
        acc[4] = fmaf(w, bflo(u.z), acc[4]);
        acc[5] = fmaf(w, bfhi(u.z), acc[5]);
        acc[6] = fmaf(w, bflo(u.w), acc[6]);
        acc[7] = fmaf(w, bfhi(u.w), acc[7]);
      }
    }
  }
  #pragma unroll
  for (int o = 1; o <= 32; o <<= 1) sum += __shfl_xor(sum, o);
  #pragma unroll
  for (int o = 8; o <= 32; o <<= 1)
    #pragma unroll
    for (int j = 0; j < 8; ++j) acc[j] += __shfl_xor(acc[j], o);
  if (g == 0) {
    float rsv = (s1 > s0) ? 1.f / sum : 0.f;
    float4 b0 = ((const float4*)bias)[cg * 2];
    float4 b1 = ((const float4*)bias)[cg * 2 + 1];
    float o[8] = {fmaf(acc[0], rsv, b0.x), fmaf(acc[1], rsv, b0.y),
                  fmaf(acc[2], rsv, b0.z), fmaf(acc[3], rsv, b0.w),
                  fmaf(acc[4], rsv, b1.x), fmaf(acc[5], rsv, b1.y),
                  fmaf(acc[6], rsv, b1.z), fmaf(acc[7], rsv, b1.w)};
    #pragma unroll
    for (int j = 0; j < 8; ++j) o[j] = (o[j] > 0.f) ? o[j] : expm1f(o[j]);
    float4* out4 = (float4*)out;
    out4[(size_t)n * 16 + cg * 2]     = make_float4(o[0], o[1], o[2], o[3]);
    out4[(size_t)n * 16 + cg * 2 + 1] = make_float4(o[4], o[5], o[6], o[7]);
  }
}

extern "C" void kernel_launch(void* const* d_in, const int* in_sizes, int n_in,
                              void* d_out, int out_size, void* d_ws, size_t ws_size,
                              hipStream_t stream) {
  const float* x   = (const float*)d_in[0];
  const int*   src = (const int*)d_in[1];
  const int*   dst = (const int*)d_in[2];
  const float* W1  = (const float*)d_in[3];
  const float* al1 = (const float*)d_in[4];
  const float* ar1 = (const float*)d_in[5];
  const float* b1  = (const float*)d_in[6];
  const float* W2  = (const float*)d_in[7];
  const float* al2 = (const float*)d_in[8];
  const float* ar2 = (const float*)d_in[9];
  const float* b2  = (const float*)d_in[10];
  float* out = (float*)d_out;

  char* ws = (char*)d_ws;
  size_t wo = 0;
  auto alloc = [&](size_t b) { void* p = ws + wo; wo = (wo + b + 255) & ~(size_t)255; return p; };
  ushort_t* ft1b = (ushort_t*)alloc((size_t)N_NODES * 256 * 2);  // reused as ft2b
  ushort_t* h1b  = (ushort_t*)alloc((size_t)N_NODES * 256 * 2);
  ushort_t* bpk1 = (ushort_t*)alloc((size_t)IN_DIM * 256 * 2);
  ushort_t* bpk2 = (ushort_t*)alloc((size_t)256 * 64 * 2);
  float* el1 = (float*)alloc((size_t)N_NODES * 4 * 4);
  float* er1 = (float*)alloc((size_t)N_NODES * 4 * 4);
  int*   off = (int*)alloc((size_t)(N_NODES + 1) * 4);
  int*   offp= (int*)alloc((size_t)N_NODES * 4);
  // zero zone: cnt | cnt2 | barrier counters (one memset covers all)
  size_t zbytes = (size_t)2 * N_NODES * 4 + 256;
  int*   zz  = (int*)alloc(zbytes);
  int*   bsum= (int*)alloc(256);
  int*   ssrc= (int*)alloc((size_t)N_EDGES * 4);
  int* cnt  = zz;
  int* cnt2 = zz + N_NODES;
  unsigned* bar = (unsigned*)(zz + 2 * N_NODES);
  ushort_t* ft2b = ft1b;
  float* el2 = el1, *er2 = er1;

  hipMemsetAsync(zz, 0, zbytes, stream);
  k_mega<<<MEGA_NB, 256, 0, stream>>>(W1, W2, bpk1, bpk2, dst, src,
                                      cnt, cnt2, bar, offp, bsum, off, ssrc,
                                      x, ft1b, al1, ar1, el1, er1);
  agg4f_k<<<(N_NODES + 3) / 4, 256, 0, stream>>>(ft1b, el1, er1, off, ssrc, b1, h1b);
  gemm2_mfma<<<391, 512, 0, stream>>>(h1b, bpk2, ft2b, al2, ar2, el2, er2, N_NODES);
  agg1f_k<<<(N_NODES + 3) / 4, 256, 0, stream>>>(ft2b, el2, er2, off, ssrc, b2, out);
}

// Round 11
// 192.965 us; speedup vs baseline: 1.7210x; 1.7210x over previous
//
#include <hip/hip_runtime.h>
#include <hip/hip_bf16.h>
#include <math.h>

#define N_NODES 50000
#define N_EDGES 800000
#define IN_DIM 128
#define HID 64
#define HEADS 4

typedef unsigned short ushort_t;
typedef __attribute__((ext_vector_type(8))) short bf16x8;
typedef __attribute__((ext_vector_type(4))) float f32x4;

static __device__ __forceinline__ ushort_t f2bf(float f) {
  __hip_bfloat16 b = __float2bfloat16(f);
  return *(ushort_t*)&b;
}
static __device__ __forceinline__ float bflo(unsigned d) {
  union { unsigned u; float f; } c; c.u = d << 16; return c.f;
}
static __device__ __forceinline__ float bfhi(unsigned d) {
  union { unsigned u; float f; } c; c.u = d & 0xffff0000u; return c.f;
}
static __device__ __forceinline__ unsigned packbf(float lo, float hi) {
  return (unsigned)f2bf(lo) | ((unsigned)f2bf(hi) << 16);
}
static __device__ __forceinline__ float lrelu(float x) {
  return (x > 0.f) ? x : 0.01f * x;
}

// ========== k1: pack W1/W2 into MFMA B-fragment layout (24 blk) + hist ======
// hist also records each edge's arrival slot -> place needs no atomics.
__global__ __launch_bounds__(256) void k_cvt_hist(const float* __restrict__ w1,
                                                  const float* __restrict__ w2,
                                                  ushort_t* __restrict__ bpk1,
                                                  ushort_t* __restrict__ bpk2,
                                                  const int* __restrict__ dst,
                                                  int* __restrict__ cnt,
                                                  int* __restrict__ slot) {
  constexpr int NP1 = 4096;   // W1 pack threads (x8 elems)
  constexpr int NP2 = 2048;   // W2 pack threads
  constexpr int CVT_BLK = (NP1 + NP2) / 256;  // 24
  int bid = blockIdx.x;
  if (bid < CVT_BLK) {
    int t = bid * 256 + threadIdx.x;
    if (t < NP1) {
      int l = t & 63, rem = t >> 6;
      int kk = rem & 3, ct = (rem >> 2) & 3, hh = rem >> 4;
      int kb = kk * 32 + (l >> 4) * 8;
      int col = hh * 64 + ct * 16 + (l & 15);
      ushort_t v[8];
      #pragma unroll
      for (int j = 0; j < 8; ++j) v[j] = f2bf(w1[(kb + j) * 256 + col]);
      *(uint4*)&bpk1[t * 8] = *(uint4*)v;
    } else {
      int u = t - NP1;
      int l = u & 63, rem = u >> 6;
      int kk = rem & 7, ct = rem >> 3;
      int kb = kk * 32 + (l >> 4) * 8;
      int col = ct * 16 + (l & 15);
      ushort_t v[8];
      #pragma unroll
      for (int j = 0; j < 8; ++j) v[j] = f2bf(w2[(kb + j) * 64 + col]);
      *(uint4*)&bpk2[u * 8] = *(uint4*)v;
    }
  } else {
    int e = (bid - CVT_BLK) * 256 + threadIdx.x;
    if (e < N_EDGES) {
      int d = dst[e];
      int p = atomicAdd(&cnt[d], 1);
      slot[e] = p;
    }
  }
}

// ======== k2: scan1 (49 blocks) + gemm1 (391 blocks, 512 thr, 128x256) ======
__global__ __launch_bounds__(512) void k_scan_gemm1(const int* __restrict__ cnt,
                                                    int* __restrict__ offp,
                                                    int* __restrict__ bsum,
                                                    const float* __restrict__ A,
                                                    const ushort_t* __restrict__ Bpk,
                                                    ushort_t* __restrict__ C,
                                                    const float* __restrict__ al,
                                                    const float* __restrict__ ar,
                                                    float* __restrict__ el,
                                                    float* __restrict__ er, int M) {
  __shared__ char smraw[128 * 40 * 2];  // 10240 B
  const int tid = threadIdx.x;
  if (blockIdx.x < 49) {
    // ---- scan1: exclusive prefix of 1024 counts, 512 thr x 2 ----
    int* lds = (int*)smraw;
    int i = blockIdx.x * 1024 + tid * 2;
    int v0 = (i < N_NODES) ? cnt[i] : 0;
    int v1 = (i + 1 < N_NODES) ? cnt[i + 1] : 0;
    int t = v0 + v1;
    lds[tid] = t;
    __syncthreads();
    for (int s = 1; s < 512; s <<= 1) {
      int u = (tid >= s) ? lds[tid - s] : 0;
      __syncthreads();
      lds[tid] += u;
      __syncthreads();
    }
    int excl = lds[tid] - t;
    if (i < N_NODES) offp[i] = excl;
    if (i + 1 < N_NODES) offp[i + 1] = excl + v0;
    if (tid == 511) bsum[blockIdx.x] = lds[511];
    return;
  }
  // ---- gemm1: tile 128 x 256, 8 waves (wave = head x row-half) ----
  ushort_t (*As)[40] = (ushort_t(*)[40])smraw;
  const int m0 = (blockIdx.x - 49) * 128;
  const int w = tid >> 6, l = tid & 63;
  const int hh = w >> 1, rh = (w & 1) * 64;
  const int lr = l & 15, lk = l >> 4;
  f32x4 acc[4][4] = {};

  #pragma unroll
  for (int kk = 0; kk < 4; ++kk) {
    int k0 = kk * 32;
    {
      int r = tid >> 2, kc = (tid & 3) * 8;
      float4 va = make_float4(0.f, 0.f, 0.f, 0.f), vb = va;
      if (m0 + r < M) {
        va = *(const float4*)&A[(size_t)(m0 + r) * IN_DIM + k0 + kc];
        vb = *(const float4*)&A[(size_t)(m0 + r) * IN_DIM + k0 + kc + 4];
      }
      uint4 p;
      p.x = packbf(va.x, va.y); p.y = packbf(va.z, va.w);
      p.z = packbf(vb.x, vb.y); p.w = packbf(vb.z, vb.w);
      *(uint4*)&As[r][kc] = p;
    }
    __syncthreads();
    bf16x8 a[4];
    #pragma unroll
    for (int rt = 0; rt < 4; ++rt) a[rt] = *(const bf16x8*)&As[rh + rt * 16 + lr][lk * 8];
    #pragma unroll
    for (int ct = 0; ct < 4; ++ct) {
      bf16x8 b = ((const bf16x8*)Bpk)[((hh * 4 + ct) * 4 + kk) * 64 + l];
      #pragma unroll
      for (int rt = 0; rt < 4; ++rt)
        acc[rt][ct] = __builtin_amdgcn_mfma_f32_16x16x32_bf16(a[rt], b, acc[rt][ct], 0, 0, 0);
    }
    __syncthreads();
  }
  // el/er epilogue (head hh)
  float ala[4], ara[4];
  #pragma unroll
  for (int ct = 0; ct < 4; ++ct) {
    ala[ct] = al[hh * 64 + ct * 16 + lr];
    ara[ct] = ar[hh * 64 + ct * 16 + lr];
  }
  #pragma unroll
  for (int rt = 0; rt < 4; ++rt)
    #pragma unroll
    for (int j = 0; j < 4; ++j) {
      float pel = 0.f, per = 0.f;
      #pragma unroll
      for (int ct = 0; ct < 4; ++ct) {
        float v = acc[rt][ct][j];
        pel = fmaf(v, ala[ct], pel);
        per = fmaf(v, ara[ct], per);
      }
      #pragma unroll
      for (int o = 1; o <= 8; o <<= 1) {
        pel += __shfl_xor(pel, o);
        per += __shfl_xor(per, o);
      }
      int row = m0 + rh + rt * 16 + lk * 4 + j;
      if (lr == 0 && row < M) { el[row * 4 + hh] = pel; er[row * 4 + hh] = per; }
    }
  #pragma unroll
  for (int rt = 0; rt < 4; ++rt)
    #pragma unroll
    for (int ct = 0; ct < 4; ++ct)
      #pragma unroll
      for (int j = 0; j < 4; ++j) {
        int row = m0 + rh + rt * 16 + lk * 4 + j;
        if (row < M) C[(size_t)row * 256 + hh * 64 + ct * 16 + lr] = f2bf(acc[rt][ct][j]);
      }
}

// ==== k3: off-finalize (49 blocks) + atomic-free place (3125 blocks) ========
__global__ __launch_bounds__(256) void k_place(const int* __restrict__ offp,
                                               const int* __restrict__ bsum,
                                               int* __restrict__ off,
                                               const int* __restrict__ src,
                                               const int* __restrict__ dst,
                                               const int* __restrict__ slot,
                                               int* __restrict__ ssrc) {
  __shared__ int pref[64];
  const int tid = threadIdx.x;
  const int bid = blockIdx.x;
  if (bid < 49) {
    if (tid < 64) {
      int v = (tid < bid) ? bsum[tid] : 0;
      #pragma unroll
      for (int o = 1; o < 64; o <<= 1) v += __shfl_xor(v, o);
      if (tid == 0) pref[0] = v;
    }
    __syncthreads();
    int e0 = pref[0];
    int i = bid * 1024 + tid * 4;
    if (i + 3 < N_NODES) {
      int4 q = *(const int4*)&offp[i];
      *(int4*)&off[i] = make_int4(q.x + e0, q.y + e0, q.z + e0, q.w + e0);
    } else {
      if (i < N_NODES) off[i] = offp[i] + e0;
      if (i + 1 < N_NODES) off[i + 1] = offp[i + 1] + e0;
      if (i + 2 < N_NODES) off[i + 2] = offp[i + 2] + e0;
      if (i + 3 < N_NODES) off[i + 3] = offp[i + 3] + e0;
    }
    if (bid == 0 && tid == 0) off[N_NODES] = N_EDGES;
    return;
  }
  if (tid < 64) {
    int v = (tid < 49) ? bsum[tid] : 0;
    int orig = v;
    #pragma unroll
    for (int o = 1; o < 64; o <<= 1) { int u = __shfl_up(v, o); if (tid >= o) v += u; }
    pref[tid] = v - orig;
  }
  __syncthreads();
  int e = (bid - 49) * 256 + tid;
  if (e < N_EDGES) {
    int d = dst[e];
    ssrc[offp[d] + pref[d >> 10] + slot[e]] = src[e];
  }
}

// ==== layer-1 agg, fused softmax ====
__global__ __launch_bounds__(256) void agg4f_k(const ushort_t* __restrict__ ftb,
                                               const float* __restrict__ el,
                                               const float* __restrict__ er,
                                               const int* __restrict__ off,
                                               const int* __restrict__ ssrc,
                                               const float* __restrict__ bias,
                                               ushort_t* __restrict__ outb) {
  __shared__ float wl[4][64][4];
  __shared__ int srcl[4][64];
  int wv = threadIdx.x >> 6, lane = threadIdx.x & 63;
  int n = blockIdx.x * 4 + wv;
  if (n >= N_NODES) return;
  int s0 = off[n], s1 = off[n + 1];
  int half = lane >> 5, sl = lane & 31;
  int head = sl >> 3;
  const float4* el4 = (const float4*)el;
  float4 erv = ((const float4*)er)[n];
  float4 sum = make_float4(0.f, 0.f, 0.f, 0.f);
  float acc[8] = {};
  for (int c = s0; c < s1; c += 64) {
    int e = c + lane;
    float4 ex = make_float4(0.f, 0.f, 0.f, 0.f);
    int s = 0;
    if (e < s1) {
      s = ssrc[e];
      float4 q = el4[s];
      ex.x = __expf(lrelu(q.x + erv.x));
      ex.y = __expf(lrelu(q.y + erv.y));
      ex.z = __expf(lrelu(q.z + erv.z));
      ex.w = __expf(lrelu(q.w + erv.w));
      sum.x += ex.x; sum.y += ex.y; sum.z += ex.z; sum.w += ex.w;
    }
    srcl[wv][lane] = s;
    *(float4*)&wl[wv][lane][0] = ex;
    int cend = (c + 64 < s1) ? c + 64 : s1;
    #pragma unroll 4
    for (int i = c; i < cend; i += 2) {
      int e2 = i + half;
      if (e2 < cend) {
        int idx = e2 - c;
        int ss = srcl[wv][idx];
        float w = wl[wv][idx][head];
        uint4 u = *(const uint4*)&ftb[ss * 256 + sl * 8];
        acc[0] = fmaf(w, bflo(u.x), acc[0]);
        acc[1] = fmaf(w, bfhi(u.x), acc[1]);
        acc[2] = fmaf(w, bflo(u.y), acc[2]);
        acc[3] = fmaf(w, bfhi(u.y), acc[3]);
        acc[4] = fmaf(w, bflo(u.z), acc[4]);
        acc[5] = fmaf(w, bfhi(u.z), acc[5]);
        acc[6] = fmaf(w, bflo(u.w), acc[6]);
        acc[7] = fmaf(w, bfhi(u.w), acc[7]);
      }
    }
  }
  #pragma unroll
  for (int o = 1; o <= 32; o <<= 1) {
    sum.x += __shfl_xor(sum.x, o); sum.y += __shfl_xor(sum.y, o);
    sum.z += __shfl_xor(sum.z, o); sum.w += __shfl_xor(sum.w, o);
  }
  #pragma unroll
  for (int j = 0; j < 8; ++j) acc[j] += __shfl_xor(acc[j], 32);
  if (half == 0) {
    float sd = (head == 0) ? sum.x : (head == 1) ? sum.y : (head == 2) ? sum.z : sum.w;
    float rsv = (s1 > s0) ? 1.f / sd : 0.f;
    float4 b0 = ((const float4*)bias)[sl * 2];
    float4 b1 = ((const float4*)bias)[sl * 2 + 1];
    float o[8] = {fmaf(acc[0], rsv, b0.x), fmaf(acc[1], rsv, b0.y),
                  fmaf(acc[2], rsv, b0.z), fmaf(acc[3], rsv, b0.w),
                  fmaf(acc[4], rsv, b1.x), fmaf(acc[5], rsv, b1.y),
                  fmaf(acc[6], rsv, b1.z), fmaf(acc[7], rsv, b1.w)};
    #pragma unroll
    for (int j = 0; j < 8; ++j) o[j] = (o[j] > 0.f) ? o[j] : expm1f(o[j]);
    uint4 p;
    p.x = packbf(o[0], o[1]); p.y = packbf(o[2], o[3]);
    p.z = packbf(o[4], o[5]); p.w = packbf(o[6], o[7]);
    *(uint4*)&outb[n * 256 + sl * 8] = p;
  }
}

// ==== layer-2 GEMM: 128x64 tile, 512 thr, pre-packed B, fused el/er ====
__global__ __launch_bounds__(512) void gemm2_mfma(const ushort_t* __restrict__ A,
                                                  const ushort_t* __restrict__ Bpk,
                                                  ushort_t* __restrict__ C,
                                                  const float* __restrict__ al,
                                                  const float* __restrict__ ar,
                                                  float* __restrict__ el,
                                                  float* __restrict__ er, int M) {
  __shared__ ushort_t As[128][40];
  const int tid = threadIdx.x;
  const int m0 = blockIdx.x * 128;
  const int w = tid >> 6, l = tid & 63;
  const int lr = l & 15, lk = l >> 4;
  f32x4 acc[4] = {};

  #pragma unroll
  for (int kk = 0; kk < 8; ++kk) {
    int k0 = kk * 32;
    {
      int r = tid >> 2, kc = (tid & 3) * 8;
      uint4 v = make_uint4(0, 0, 0, 0);
      if (m0 + r < M) v = *(const uint4*)&A[(size_t)(m0 + r) * 256 + k0 + kc];
      *(uint4*)&As[r][kc] = v;
    }
    __syncthreads();
    bf16x8 a = *(const bf16x8*)&As[w * 16 + lr][lk * 8];
    #pragma unroll
    for (int ct = 0; ct < 4; ++ct) {
      bf16x8 b = ((const bf16x8*)Bpk)[(ct * 8 + kk) * 64 + l];
      acc[ct] = __builtin_amdgcn_mfma_f32_16x16x32_bf16(a, b, acc[ct], 0, 0, 0);
    }
    __syncthreads();
  }
  float ala[4], ara[4];
  #pragma unroll
  for (int ct = 0; ct < 4; ++ct) {
    ala[ct] = al[ct * 16 + lr];
    ara[ct] = ar[ct * 16 + lr];
  }
  #pragma unroll
  for (int j = 0; j < 4; ++j) {
    float pel = 0.f, per = 0.f;
    #pragma unroll
    for (int ct = 0; ct < 4; ++ct) {
      float v = acc[ct][j];
      pel = fmaf(v, ala[ct], pel);
      per = fmaf(v, ara[ct], per);
    }
    #pragma unroll
    for (int o = 1; o <= 8; o <<= 1) {
      pel += __shfl_xor(pel, o);
      per += __shfl_xor(per, o);
    }
    int row = m0 + w * 16 + lk * 4 + j;
    if (lr == 0 && row < M) { el[row] = pel; er[row] = per; }
  }
  #pragma unroll
  for (int ct = 0; ct < 4; ++ct)
    #pragma unroll
    for (int j = 0; j < 4; ++j) {
      int row = m0 + w * 16 + lk * 4 + j;
      if (row < M) C[(size_t)row * 64 + ct * 16 + lr] = f2bf(acc[ct][j]);
    }
}

// ==== layer-2 agg, fused softmax ====
__global__ __launch_bounds__(256) void agg1f_k(const ushort_t* __restrict__ ftb,
                                               const float* __restrict__ el,
                                               const float* __restrict__ er,
                                               const int* __restrict__ off,
                                               const int* __restrict__ ssrc,
                                               const float* __restrict__ bias,
                                               float* __restrict__ out) {
  __shared__ float wl[4][64];
  __shared__ int srcl[4][64];
  int wv = threadIdx.x >> 6, lane = threadIdx.x & 63;
  int n = blockIdx.x * 4 + wv;
  if (n >= N_NODES) return;
  int s0 = off[n], s1 = off[n + 1];
  int g = lane >> 3, cg = lane & 7;
  float erv = er[n];
  float sum = 0.f;
  float acc[8] = {};
  for (int c = s0; c < s1; c += 64) {
    int e = c + lane;
    float ex = 0.f;
    int s = 0;
    if (e < s1) {
      s = ssrc[e];
      ex = __expf(lrelu(el[s] + erv));
      sum += ex;
    }
    srcl[wv][lane] = s;
    wl[wv][lane] = ex;
    int cend = (c + 64 < s1) ? c + 64 : s1;
    #pragma unroll 2
    for (int i = c; i < cend; i += 8) {
      int e2 = i + g;
      if (e2 < cend) {
        int idx = e2 - c;
        int ss = srcl[wv][idx];
        float w = wl[wv][idx];
        uint4 u = *(const uint4*)&ftb[ss * 64 + cg * 8];
        acc[0] = fmaf(w, bflo(u.x), acc[0]);
        acc[1] = fmaf(w, bfhi(u.x), acc[1]);
        acc[2] = fmaf(w, bflo(u.y), acc[2]);
        acc[3] = fmaf(w, bfhi(u.y), acc[3]);
        acc[4] = fmaf(w, bflo(u.z), acc[4]);
        acc[5] = fmaf(w, bfhi(u.z), acc[5]);
        acc[6] = fmaf(w, bflo(u.w), acc[6]);
        acc[7] = fmaf(w, bfhi(u.w), acc[7]);
      }
    }
  }
  #pragma unroll
  for (int o = 1; o <= 32; o <<= 1) sum += __shfl_xor(sum, o);
  #pragma unroll
  for (int o = 8; o <= 32; o <<= 1)
    #pragma unroll
    for (int j = 0; j < 8; ++j) acc[j] += __shfl_xor(acc[j], o);
  if (g == 0) {
    float rsv = (s1 > s0) ? 1.f / sum : 0.f;
    float4 b0 = ((const float4*)bias)[cg * 2];
    float4 b1 = ((const float4*)bias)[cg * 2 + 1];
    float o[8] = {fmaf(acc[0], rsv, b0.x), fmaf(acc[1], rsv, b0.y),
                  fmaf(acc[2], rsv, b0.z), fmaf(acc[3], rsv, b0.w),
                  fmaf(acc[4], rsv, b1.x), fmaf(acc[5], rsv, b1.y),
                  fmaf(acc[6], rsv, b1.z), fmaf(acc[7], rsv, b1.w)};
    #pragma unroll
    for (int j = 0; j < 8; ++j) o[j] = (o[j] > 0.f) ? o[j] : expm1f(o[j]);
    float4* out4 = (float4*)out;
    out4[(size_t)n * 16 + cg * 2]     = make_float4(o[0], o[1], o[2], o[3]);
    out4[(size_t)n * 16 + cg * 2 + 1] = make_float4(o[4], o[5], o[6], o[7]);
  }
}

extern "C" void kernel_launch(void* const* d_in, const int* in_sizes, int n_in,
                              void* d_out, int out_size, void* d_ws, size_t ws_size,
                              hipStream_t stream) {
  const float* x   = (const float*)d_in[0];
  const int*   src = (const int*)d_in[1];
  const int*   dst = (const int*)d_in[2];
  const float* W1  = (const float*)d_in[3];
  const float* al1 = (const float*)d_in[4];
  const float* ar1 = (const float*)d_in[5];
  const float* b1  = (const float*)d_in[6];
  const float* W2  = (const float*)d_in[7];
  const float* al2 = (const float*)d_in[8];
  const float* ar2 = (const float*)d_in[9];
  const float* b2  = (const float*)d_in[10];
  float* out = (float*)d_out;

  char* ws = (char*)d_ws;
  size_t wo = 0;
  auto alloc = [&](size_t b) { void* p = ws + wo; wo = (wo + b + 255) & ~(size_t)255; return p; };
  ushort_t* ft1b = (ushort_t*)alloc((size_t)N_NODES * 256 * 2);  // reused as ft2b
  ushort_t* h1b  = (ushort_t*)alloc((size_t)N_NODES * 256 * 2);
  ushort_t* bpk1 = (ushort_t*)alloc((size_t)IN_DIM * 256 * 2);
  ushort_t* bpk2 = (ushort_t*)alloc((size_t)256 * 64 * 2);
  float* el1 = (float*)alloc((size_t)N_NODES * 4 * 4);
  float* er1 = (float*)alloc((size_t)N_NODES * 4 * 4);
  int*   off = (int*)alloc((size_t)(N_NODES + 1) * 4);
  int*   offp= (int*)alloc((size_t)N_NODES * 4);
  int*   cnt = (int*)alloc((size_t)N_NODES * 4);
  int*   slot= (int*)alloc((size_t)N_EDGES * 4);
  int*   bsum= (int*)alloc(256);
  int*   ssrc= (int*)alloc((size_t)N_EDGES * 4);
  ushort_t* ft2b = ft1b;
  float* el2 = el1, *er2 = er1;

  hipMemsetAsync(cnt, 0, (size_t)N_NODES * 4, stream);
  k_cvt_hist<<<24 + 3125, 256, 0, stream>>>(W1, W2, bpk1, bpk2, dst, cnt, slot);
  k_scan_gemm1<<<49 + 391, 512, 0, stream>>>(cnt, offp, bsum,
                                             x, bpk1, ft1b, al1, ar1, el1, er1, N_NODES);
  k_place<<<49 + 3125, 256, 0, stream>>>(offp, bsum, off, src, dst, slot, ssrc);
  agg4f_k<<<(N_NODES + 3) / 4, 256, 0, stream>>>(ft1b, el1, er1, off, ssrc, b1, h1b);
  gemm2_mfma<<<391, 512, 0, stream>>>(h1b, bpk2, ft2b, al2, ar2, el2, er2, N_NODES);
  agg1f_k<<<(N_NODES + 3) / 4, 256, 0, stream>>>(ft2b, el2, er2, off, ssrc, b2, out);
}

// Round 13
// 188.119 us; speedup vs baseline: 1.7653x; 1.0258x over previous
//
#include <hip/hip_runtime.h>
#include <hip/hip_bf16.h>
#include <math.h>

#define N_NODES 50000
#define N_EDGES 800000
#define IN_DIM 128
#define HID 64
#define HEADS 4

typedef unsigned short ushort_t;
typedef __attribute__((ext_vector_type(8))) short bf16x8;
typedef __attribute__((ext_vector_type(4))) float f32x4;

static __device__ __forceinline__ ushort_t f2bf(float f) {
  __hip_bfloat16 b = __float2bfloat16(f);
  return *(ushort_t*)&b;
}
static __device__ __forceinline__ float bflo(unsigned d) {
  union { unsigned u; float f; } c; c.u = d << 16; return c.f;
}
static __device__ __forceinline__ float bfhi(unsigned d) {
  union { unsigned u; float f; } c; c.u = d & 0xffff0000u; return c.f;
}
static __device__ __forceinline__ unsigned packbf(float lo, float hi) {
  return (unsigned)f2bf(lo) | ((unsigned)f2bf(hi) << 16);
}
static __device__ __forceinline__ float lrelu(float x) {
  return (x > 0.f) ? x : 0.01f * x;
}

// ==== k0: pack W1/W2 into MFMA B-fragment layout (12 blocks x 512 thr) ====
// MUST be a separate dispatch: gemm1 (in k1) consumes bpk1.
__global__ __launch_bounds__(512) void k0_pack(const float* __restrict__ w1,
                                               const float* __restrict__ w2,
                                               ushort_t* __restrict__ bpk1,
                                               ushort_t* __restrict__ bpk2) {
  int t = blockIdx.x * 512 + threadIdx.x;
  if (t < 4096) {
    int l = t & 63, rem = t >> 6;
    int kk = rem & 3, ct = (rem >> 2) & 3, hh = rem >> 4;
    int kb = kk * 32 + (l >> 4) * 8;
    int col = hh * 64 + ct * 16 + (l & 15);
    ushort_t v[8];
    #pragma unroll
    for (int j = 0; j < 8; ++j) v[j] = f2bf(w1[(kb + j) * 256 + col]);
    *(uint4*)&bpk1[t * 8] = *(uint4*)v;
  } else if (t < 6144) {
    int u = t - 4096;
    int l = u & 63, rem = u >> 6;
    int kk = rem & 7, ct = rem >> 3;
    int kb = kk * 32 + (l >> 4) * 8;
    int col = ct * 16 + (l & 15);
    ushort_t v[8];
    #pragma unroll
    for (int j = 0; j < 8; ++j) v[j] = f2bf(w2[(kb + j) * 64 + col]);
    *(uint4*)&bpk2[u * 8] = *(uint4*)v;
  }
}

// ==== k1: gemm1 (391 blk) ∥ hist+slot (1563 blk) — independent phases ====
__global__ __launch_bounds__(512) void k_gemm1_hist(
    const float* __restrict__ A, const ushort_t* __restrict__ Bpk,
    ushort_t* __restrict__ C, const float* __restrict__ al,
    const float* __restrict__ ar, float* __restrict__ el,
    float* __restrict__ er,
    const int* __restrict__ dst, int* __restrict__ cnt,
    int* __restrict__ slot) {
  __shared__ ushort_t As[128][40];
  const int tid = threadIdx.x;
  const int bid = blockIdx.x;
  if (bid >= 391) {
    // ---- hist: record arrival slot so place needs no atomics ----
    int e = (bid - 391) * 512 + tid;
    if (e < N_EDGES) {
      int d = dst[e];
      int p = atomicAdd(&cnt[d], 1);
      slot[e] = p;
    }
    return;
  }
  // ---- gemm1: tile 128 x 256, 8 waves (wave = head x row-half) ----
  const int m0 = bid * 128;
  const int w = tid >> 6, l = tid & 63;
  const int hh = w >> 1, rh = (w & 1) * 64;
  const int lr = l & 15, lk = l >> 4;
  f32x4 acc[4][4] = {};

  #pragma unroll
  for (int kk = 0; kk < 4; ++kk) {
    int k0 = kk * 32;
    {
      int r = tid >> 2, kc = (tid & 3) * 8;
      float4 va = make_float4(0.f, 0.f, 0.f, 0.f), vb = va;
      if (m0 + r < N_NODES) {
        va = *(const float4*)&A[(size_t)(m0 + r) * IN_DIM + k0 + kc];
        vb = *(const float4*)&A[(size_t)(m0 + r) * IN_DIM + k0 + kc + 4];
      }
      uint4 p;
      p.x = packbf(va.x, va.y); p.y = packbf(va.z, va.w);
      p.z = packbf(vb.x, vb.y); p.w = packbf(vb.z, vb.w);
      *(uint4*)&As[r][kc] = p;
    }
    __syncthreads();
    bf16x8 a[4];
    #pragma unroll
    for (int rt = 0; rt < 4; ++rt) a[rt] = *(const bf16x8*)&As[rh + rt * 16 + lr][lk * 8];
    #pragma unroll
    for (int ct = 0; ct < 4; ++ct) {
      bf16x8 b = ((const bf16x8*)Bpk)[((hh * 4 + ct) * 4 + kk) * 64 + l];
      #pragma unroll
      for (int rt = 0; rt < 4; ++rt)
        acc[rt][ct] = __builtin_amdgcn_mfma_f32_16x16x32_bf16(a[rt], b, acc[rt][ct], 0, 0, 0);
    }
    __syncthreads();
  }
  float ala[4], ara[4];
  #pragma unroll
  for (int ct = 0; ct < 4; ++ct) {
    ala[ct] = al[hh * 64 + ct * 16 + lr];
    ara[ct] = ar[hh * 64 + ct * 16 + lr];
  }
  #pragma unroll
  for (int rt = 0; rt < 4; ++rt)
    #pragma unroll
    for (int j = 0; j < 4; ++j) {
      float pel = 0.f, per = 0.f;
      #pragma unroll
      for (int ct = 0; ct < 4; ++ct) {
        float v = acc[rt][ct][j];
        pel = fmaf(v, ala[ct], pel);
        per = fmaf(v, ara[ct], per);
      }
      #pragma unroll
      for (int o = 1; o <= 8; o <<= 1) {
        pel += __shfl_xor(pel, o);
        per += __shfl_xor(per, o);
      }
      int row = m0 + rh + rt * 16 + lk * 4 + j;
      if (lr == 0 && row < N_NODES) { el[row * 4 + hh] = pel; er[row * 4 + hh] = per; }
    }
  #pragma unroll
  for (int rt = 0; rt < 4; ++rt)
    #pragma unroll
    for (int ct = 0; ct < 4; ++ct)
      #pragma unroll
      for (int j = 0; j < 4; ++j) {
        int row = m0 + rh + rt * 16 + lk * 4 + j;
        if (row < N_NODES) C[(size_t)row * 256 + hh * 64 + ct * 16 + lr] = f2bf(acc[rt][ct][j]);
      }
}

// ==== k2: scan1 (49 blocks @ 512 thr) ====
__global__ __launch_bounds__(512) void k_scan(const int* __restrict__ cnt,
                                              int* __restrict__ offp,
                                              int* __restrict__ bsum) {
  __shared__ int lds[512];
  const int tid = threadIdx.x;
  int i = blockIdx.x * 1024 + tid * 2;
  int v0 = (i < N_NODES) ? cnt[i] : 0;
  int v1 = (i + 1 < N_NODES) ? cnt[i + 1] : 0;
  int t = v0 + v1;
  lds[tid] = t;
  __syncthreads();
  for (int s = 1; s < 512; s <<= 1) {
    int u = (tid >= s) ? lds[tid - s] : 0;
    __syncthreads();
    lds[tid] += u;
    __syncthreads();
  }
  int excl = lds[tid] - t;
  if (i < N_NODES) offp[i] = excl;
  if (i + 1 < N_NODES) offp[i + 1] = excl + v0;
  if (tid == 511) bsum[blockIdx.x] = lds[511];
}

// ==== k3: off-finalize (49 blk) + atomic-free place, 4 edges/thread (782) ====
__global__ __launch_bounds__(256) void k_place(const int* __restrict__ offp,
                                               const int* __restrict__ bsum,
                                               int* __restrict__ off,
                                               const int* __restrict__ src,
                                               const int* __restrict__ dst,
                                               const int* __restrict__ slot,
                                               int* __restrict__ ssrc) {
  __shared__ int pref[64];
  const int tid = threadIdx.x;
  const int bid = blockIdx.x;
  if (bid < 49) {
    if (tid < 64) {
      int v = (tid < bid) ? bsum[tid] : 0;
      #pragma unroll
      for (int o = 1; o < 64; o <<= 1) v += __shfl_xor(v, o);
      if (tid == 0) pref[0] = v;
    }
    __syncthreads();
    int e0 = pref[0];
    int i = bid * 1024 + tid * 4;
    if (i + 3 < N_NODES) {
      int4 q = *(const int4*)&offp[i];
      *(int4*)&off[i] = make_int4(q.x + e0, q.y + e0, q.z + e0, q.w + e0);
    } else {
      if (i < N_NODES) off[i] = offp[i] + e0;
      if (i + 1 < N_NODES) off[i + 1] = offp[i + 1] + e0;
      if (i + 2 < N_NODES) off[i + 2] = offp[i + 2] + e0;
      if (i + 3 < N_NODES) off[i + 3] = offp[i + 3] + e0;
    }
    if (bid == 0 && tid == 0) off[N_NODES] = N_EDGES;
    return;
  }
  if (tid < 64) {
    int v = (tid < 49) ? bsum[tid] : 0;
    int orig = v;
    #pragma unroll
    for (int o = 1; o < 64; o <<= 1) { int u = __shfl_up(v, o); if (tid >= o) v += u; }
    pref[tid] = v - orig;
  }
  __syncthreads();
  int e0 = (bid - 49) * 1024 + tid * 4;
  if (e0 < N_EDGES) {  // N_EDGES % 4 == 0: groups are all-in or all-out
    int4 d4 = *(const int4*)&dst[e0];
    int4 s4 = *(const int4*)&src[e0];
    int4 p4 = *(const int4*)&slot[e0];
    ssrc[offp[d4.x] + pref[d4.x >> 10] + p4.x] = s4.x;
    ssrc[offp[d4.y] + pref[d4.y >> 10] + p4.y] = s4.y;
    ssrc[offp[d4.z] + pref[d4.z >> 10] + p4.z] = s4.z;
    ssrc[offp[d4.w] + pref[d4.w >> 10] + p4.w] = s4.w;
  }
}

// ==== layer-1 agg, fused softmax ====
__global__ __launch_bounds__(256) void agg4f_k(const ushort_t* __restrict__ ftb,
                                               const float* __restrict__ el,
                                               const float* __restrict__ er,
                                               const int* __restrict__ off,
                                               const int* __restrict__ ssrc,
                                               const float* __restrict__ bias,
                                               ushort_t* __restrict__ outb) {
  __shared__ float wl[4][64][4];
  __shared__ int srcl[4][64];
  int wv = threadIdx.x >> 6, lane = threadIdx.x & 63;
  int n = blockIdx.x * 4 + wv;
  if (n >= N_NODES) return;
  int s0 = off[n], s1 = off[n + 1];
  int half = lane >> 5, sl = lane & 31;
  int head = sl >> 3;
  const float4* el4 = (const float4*)el;
  float4 erv = ((const float4*)er)[n];
  float4 sum = make_float4(0.f, 0.f, 0.f, 0.f);
  float acc[8] = {};
  for (int c = s0; c < s1; c += 64) {
    int e = c + lane;
    float4 ex = make_float4(0.f, 0.f, 0.f, 0.f);
    int s = 0;
    if (e < s1) {
      s = ssrc[e];
      float4 q = el4[s];
      ex.x = __expf(lrelu(q.x + erv.x));
      ex.y = __expf(lrelu(q.y + erv.y));
      ex.z = __expf(lrelu(q.z + erv.z));
      ex.w = __expf(lrelu(q.w + erv.w));
      sum.x += ex.x; sum.y += ex.y; sum.z += ex.z; sum.w += ex.w;
    }
    srcl[wv][lane] = s;
    *(float4*)&wl[wv][lane][0] = ex;
    int cend = (c + 64 < s1) ? c + 64 : s1;
    #pragma unroll 4
    for (int i = c; i < cend; i += 2) {
      int e2 = i + half;
      if (e2 < cend) {
        int idx = e2 - c;
        int ss = srcl[wv][idx];
        float w = wl[wv][idx][head];
        uint4 u = *(const uint4*)&ftb[ss * 256 + sl * 8];
        acc[0] = fmaf(w, bflo(u.x), acc[0]);
        acc[1] = fmaf(w, bfhi(u.x), acc[1]);
        acc[2] = fmaf(w, bflo(u.y), acc[2]);
        acc[3] = fmaf(w, bfhi(u.y), acc[3]);
        acc[4] = fmaf(w, bflo(u.z), acc[4]);
        acc[5] = fmaf(w, bfhi(u.z), acc[5]);
        acc[6] = fmaf(w, bflo(u.w), acc[6]);
        acc[7] = fmaf(w, bfhi(u.w), acc[7]);
      }
    }
  }
  #pragma unroll
  for (int o = 1; o <= 32; o <<= 1) {
    sum.x += __shfl_xor(sum.x, o); sum.y += __shfl_xor(sum.y, o);
    sum.z += __shfl_xor(sum.z, o); sum.w += __shfl_xor(sum.w, o);
  }
  #pragma unroll
  for (int j = 0; j < 8; ++j) acc[j] += __shfl_xor(acc[j], 32);
  if (half == 0) {
    float sd = (head == 0) ? sum.x : (head == 1) ? sum.y : (head == 2) ? sum.z : sum.w;
    float rsv = (s1 > s0) ? 1.f / sd : 0.f;
    float4 b0 = ((const float4*)bias)[sl * 2];
    float4 b1 = ((const float4*)bias)[sl * 2 + 1];
    float o[8] = {fmaf(acc[0], rsv, b0.x), fmaf(acc[1], rsv, b0.y),
                  fmaf(acc[2], rsv, b0.z), fmaf(acc[3], rsv, b0.w),
                  fmaf(acc[4], rsv, b1.x), fmaf(acc[5], rsv, b1.y),
                  fmaf(acc[6], rsv, b1.z), fmaf(acc[7], rsv, b1.w)};
    #pragma unroll
    for (int j = 0; j < 8; ++j) o[j] = (o[j] > 0.f) ? o[j] : expm1f(o[j]);
    uint4 p;
    p.x = packbf(o[0], o[1]); p.y = packbf(o[2], o[3]);
    p.z = packbf(o[4], o[5]); p.w = packbf(o[6], o[7]);
    *(uint4*)&outb[n * 256 + sl * 8] = p;
  }
}

// ==== layer-2 GEMM: 128x64 tile, 512 thr, pre-packed B, fused el/er ====
__global__ __launch_bounds__(512) void gemm2_mfma(const ushort_t* __restrict__ A,
                                                  const ushort_t* __restrict__ Bpk,
                                                  ushort_t* __restrict__ C,
                                                  const float* __restrict__ al,
                                                  const float* __restrict__ ar,
                                                  float* __restrict__ el,
                                                  float* __restrict__ er, int M) {
  __shared__ ushort_t As[128][40];
  const int tid = threadIdx.x;
  const int m0 = blockIdx.x * 128;
  const int w = tid >> 6, l = tid & 63;
  const int lr = l & 15, lk = l >> 4;
  f32x4 acc[4] = {};

  #pragma unroll
  for (int kk = 0; kk < 8; ++kk) {
    int k0 = kk * 32;
    {
      int r = tid >> 2, kc = (tid & 3) * 8;
      uint4 v = make_uint4(0, 0, 0, 0);
      if (m0 + r < M) v = *(const uint4*)&A[(size_t)(m0 + r) * 256 + k0 + kc];
      *(uint4*)&As[r][kc] = v;
    }
    __syncthreads();
    bf16x8 a = *(const bf16x8*)&As[w * 16 + lr][lk * 8];
    #pragma unroll
    for (int ct = 0; ct < 4; ++ct) {
      bf16x8 b = ((const bf16x8*)Bpk)[(ct * 8 + kk) * 64 + l];
      acc[ct] = __builtin_amdgcn_mfma_f32_16x16x32_bf16(a, b, acc[ct], 0, 0, 0);
    }
    __syncthreads();
  }
  float ala[4], ara[4];
  #pragma unroll
  for (int ct = 0; ct < 4; ++ct) {
    ala[ct] = al[ct * 16 + lr];
    ara[ct] = ar[ct * 16 + lr];
  }
  #pragma unroll
  for (int j = 0; j < 4; ++j) {
    float pel = 0.f, per = 0.f;
    #pragma unroll
    for (int ct = 0; ct < 4; ++ct) {
      float v = acc[ct][j];
      pel = fmaf(v, ala[ct], pel);
      per = fmaf(v, ara[ct], per);
    }
    #pragma unroll
    for (int o = 1; o <= 8; o <<= 1) {
      pel += __shfl_xor(pel, o);
      per += __shfl_xor(per, o);
    }
    int row = m0 + w * 16 + lk * 4 + j;
    if (lr == 0 && row < M) { el[row] = pel; er[row] = per; }
  }
  #pragma unroll
  for (int ct = 0; ct < 4; ++ct)
    #pragma unroll
    for (int j = 0; j < 4; ++j) {
      int row = m0 + w * 16 + lk * 4 + j;
      if (row < M) C[(size_t)row * 64 + ct * 16 + lr] = f2bf(acc[ct][j]);
    }
}

// ==== layer-2 agg, fused softmax ====
__global__ __launch_bounds__(256) void agg1f_k(const ushort_t* __restrict__ ftb,
                                               const float* __restrict__ el,
                                               const float* __restrict__ er,
                                               const int* __restrict__ off,
                                               const int* __restrict__ ssrc,
                                               const float* __restrict__ bias,
                                               float* __restrict__ out) {
  __shared__ float wl[4][64];
  __shared__ int srcl[4][64];
  int wv = threadIdx.x >> 6, lane = threadIdx.x & 63;
  int n = blockIdx.x * 4 + wv;
  if (n >= N_NODES) return;
  int s0 = off[n], s1 = off[n + 1];
  int g = lane >> 3, cg = lane & 7;
  float erv = er[n];
  float sum = 0.f;
  float acc[8] = {};
  for (int c = s0; c < s1; c += 64) {
    int e = c + lane;
    float ex = 0.f;
    int s = 0;
    if (e < s1) {
      s = ssrc[e];
      ex = __expf(lrelu(el[s] + erv));
      sum += ex;
    }
    srcl[wv][lane] = s;
    wl[wv][lane] = ex;
    int cend = (c + 64 < s1) ? c + 64 : s1;
    #pragma unroll 2
    for (int i = c; i < cend; i += 8) {
      int e2 = i + g;
      if (e2 < cend) {
        int idx = e2 - c;
        int ss = srcl[wv][idx];
        float w = wl[wv][idx];
        uint4 u = *(const uint4*)&ftb[ss * 64 + cg * 8];
        acc[0] = fmaf(w, bflo(u.x), acc[0]);
        acc[1] = fmaf(w, bfhi(u.x), acc[1]);
        acc[2] = fmaf(w, bflo(u.y), acc[2]);
        acc[3] = fmaf(w, bfhi(u.y), acc[3]);
        acc[4] = fmaf(w, bflo(u.z), acc[4]);
        acc[5] = fmaf(w, bfhi(u.z), acc[5]);
        acc[6] = fmaf(w, bflo(u.w), acc[6]);
        acc[7] = fmaf(w, bfhi(u.w), acc[7]);
      }
    }
  }
  #pragma unroll
  for (int o = 1; o <= 32; o <<= 1) sum += __shfl_xor(sum, o);
  #pragma unroll
  for (int o = 8; o <= 32; o <<= 1)
    #pragma unroll
    for (int j = 0; j < 8; ++j) acc[j] += __shfl_xor(acc[j], o);
  if (g == 0) {
    float rsv = (s1 > s0) ? 1.f / sum : 0.f;
    float4 b0 = ((const float4*)bias)[cg * 2];
    float4 b1 = ((const float4*)bias)[cg * 2 + 1];
    float o[8] = {fmaf(acc[0], rsv, b0.x), fmaf(acc[1], rsv, b0.y),
                  fmaf(acc[2], rsv, b0.z), fmaf(acc[3], rsv, b0.w),
                  fmaf(acc[4], rsv, b1.x), fmaf(acc[5], rsv, b1.y),
                  fmaf(acc[6], rsv, b1.z), fmaf(acc[7], rsv, b1.w)};
    #pragma unroll
    for (int j = 0; j < 8; ++j) o[j] = (o[j] > 0.f) ? o[j] : expm1f(o[j]);
    float4* out4 = (float4*)out;
    out4[(size_t)n * 16 + cg * 2]     = make_float4(o[0], o[1], o[2], o[3]);
    out4[(size_t)n * 16 + cg * 2 + 1] = make_float4(o[4], o[5], o[6], o[7]);
  }
}

extern "C" void kernel_launch(void* const* d_in, const int* in_sizes, int n_in,
                              void* d_out, int out_size, void* d_ws, size_t ws_size,
                              hipStream_t stream) {
  const float* x   = (const float*)d_in[0];
  const int*   src = (const int*)d_in[1];
  const int*   dst = (const int*)d_in[2];
  const float* W1  = (const float*)d_in[3];
  const float* al1 = (const float*)d_in[4];
  const float* ar1 = (const float*)d_in[5];
  const float* b1  = (const float*)d_in[6];
  const float* W2  = (const float*)d_in[7];
  const float* al2 = (const float*)d_in[8];
  const float* ar2 = (const float*)d_in[9];
  const float* b2  = (const float*)d_in[10];
  float* out = (float*)d_out;

  char* ws = (char*)d_ws;
  size_t wo = 0;
  auto alloc = [&](size_t b) { void* p = ws + wo; wo = (wo + b + 255) & ~(size_t)255; return p; };
  ushort_t* ft1b = (ushort_t*)alloc((size_t)N_NODES * 256 * 2);  // reused as ft2b
  ushort_t* h1b  = (ushort_t*)alloc((size_t)N_NODES * 256 * 2);
  ushort_t* bpk1 = (ushort_t*)alloc((size_t)IN_DIM * 256 * 2);
  ushort_t* bpk2 = (ushort_t*)alloc((size_t)256 * 64 * 2);
  float* el1 = (float*)alloc((size_t)N_NODES * 4 * 4);
  float* er1 = (float*)alloc((size_t)N_NODES * 4 * 4);
  int*   off = (int*)alloc((size_t)(N_NODES + 1) * 4);
  int*   offp= (int*)alloc((size_t)N_NODES * 4);
  int*   cnt = (int*)alloc((size_t)N_NODES * 4);
  int*   slot= (int*)alloc((size_t)N_EDGES * 4);
  int*   bsum= (int*)alloc(256);
  int*   ssrc= (int*)alloc((size_t)N_EDGES * 4);
  ushort_t* ft2b = ft1b;
  float* el2 = el1, *er2 = er1;

  hipMemsetAsync(cnt, 0, (size_t)N_NODES * 4, stream);
  k0_pack<<<12, 512, 0, stream>>>(W1, W2, bpk1, bpk2);
  // k1: gemm1 [0,391) | hist [391, 391+1563)
  k_gemm1_hist<<<391 + 1563, 512, 0, stream>>>(
      x, bpk1, ft1b, al1, ar1, el1, er1, dst, cnt, slot);
  k_scan<<<49, 512, 0, stream>>>(cnt, offp, bsum);
  k_place<<<49 + 782, 256, 0, stream>>>(offp, bsum, off, src, dst, slot, ssrc);
  agg4f_k<<<(N_NODES + 3) / 4, 256, 0, stream>>>(ft1b, el1, er1, off, ssrc, b1, h1b);
  gemm2_mfma<<<391, 512, 0, stream>>>(h1b, bpk2, ft2b, al2, ar2, el2, er2, N_NODES);
  agg1f_k<<<(N_NODES + 3) / 4, 256, 0, stream>>>(ft2b, el2, er2, off, ssrc, b2, out);
}

// Round 14
// 186.767 us; speedup vs baseline: 1.7781x; 1.0072x over previous
//
#include <hip/hip_runtime.h>
#include <hip/hip_bf16.h>
#include <math.h>

#define N_NODES 50000
#define N_EDGES 800000
#define IN_DIM 128
#define HID 64
#define HEADS 4

typedef unsigned short ushort_t;
typedef __attribute__((ext_vector_type(8))) short bf16x8;
typedef __attribute__((ext_vector_type(4))) float f32x4;

static __device__ __forceinline__ ushort_t f2bf(float f) {
  __hip_bfloat16 b = __float2bfloat16(f);
  return *(ushort_t*)&b;
}
static __device__ __forceinline__ float bflo(unsigned d) {
  union { unsigned u; float f; } c; c.u = d << 16; return c.f;
}
static __device__ __forceinline__ float bfhi(unsigned d) {
  union { unsigned u; float f; } c; c.u = d & 0xffff0000u; return c.f;
}
static __device__ __forceinline__ unsigned packbf(float lo, float hi) {
  return (unsigned)f2bf(lo) | ((unsigned)f2bf(hi) << 16);
}
static __device__ __forceinline__ float lrelu(float x) {
  return (x > 0.f) ? x : 0.01f * x;
}

// ==== k0: pack W1/W2 into MFMA B-frag layout + zero cnt (12 blk x 512) ====
// Separate dispatch from gemm1 (which consumes bpk1) and hist (consumes cnt=0).
__global__ __launch_bounds__(512) void k0_pack(const float* __restrict__ w1,
                                               const float* __restrict__ w2,
                                               ushort_t* __restrict__ bpk1,
                                               ushort_t* __restrict__ bpk2,
                                               int* __restrict__ cnt) {
  int t = blockIdx.x * 512 + threadIdx.x;
  // zero cnt: grid-stride over 50000 ints with 6144 threads
  for (int i = t; i < N_NODES; i += 12 * 512) cnt[i] = 0;
  if (t < 4096) {
    int l = t & 63, rem = t >> 6;
    int kk = rem & 3, ct = (rem >> 2) & 3, hh = rem >> 4;
    int kb = kk * 32 + (l >> 4) * 8;
    int col = hh * 64 + ct * 16 + (l & 15);
    ushort_t v[8];
    #pragma unroll
    for (int j = 0; j < 8; ++j) v[j] = f2bf(w1[(kb + j) * 256 + col]);
    *(uint4*)&bpk1[t * 8] = *(uint4*)v;
  } else if (t < 6144) {
    int u = t - 4096;
    int l = u & 63, rem = u >> 6;
    int kk = rem & 7, ct = rem >> 3;
    int kb = kk * 32 + (l >> 4) * 8;
    int col = ct * 16 + (l & 15);
    ushort_t v[8];
    #pragma unroll
    for (int j = 0; j < 8; ++j) v[j] = f2bf(w2[(kb + j) * 64 + col]);
    *(uint4*)&bpk2[u * 8] = *(uint4*)v;
  }
}

// ==== k1: gemm1 (391 blk) ∥ hist+slot 4 edges/thr (391 blk) ====
__global__ __launch_bounds__(512) void k_gemm1_hist(
    const float* __restrict__ A, const ushort_t* __restrict__ Bpk,
    ushort_t* __restrict__ C, const float* __restrict__ al,
    const float* __restrict__ ar, float* __restrict__ el,
    float* __restrict__ er,
    const int* __restrict__ dst, int* __restrict__ cnt,
    int* __restrict__ slot) {
  __shared__ ushort_t As[128][40];
  const int tid = threadIdx.x;
  const int bid = blockIdx.x;
  if (bid >= 391) {
    // ---- hist: 4 edges/thread, record arrival slots ----
    int e0 = ((bid - 391) * 512 + tid) * 4;
    if (e0 < N_EDGES) {  // N_EDGES % 4 == 0
      int4 d4 = *(const int4*)&dst[e0];
      int4 p4;
      p4.x = atomicAdd(&cnt[d4.x], 1);
      p4.y = atomicAdd(&cnt[d4.y], 1);
      p4.z = atomicAdd(&cnt[d4.z], 1);
      p4.w = atomicAdd(&cnt[d4.w], 1);
      *(int4*)&slot[e0] = p4;
    }
    return;
  }
  // ---- gemm1: tile 128 x 256, 8 waves (wave = head x row-half) ----
  const int m0 = bid * 128;
  const int w = tid >> 6, l = tid & 63;
  const int hh = w >> 1, rh = (w & 1) * 64;
  const int lr = l & 15, lk = l >> 4;
  f32x4 acc[4][4] = {};

  #pragma unroll
  for (int kk = 0; kk < 4; ++kk) {
    int k0 = kk * 32;
    {
      int r = tid >> 2, kc = (tid & 3) * 8;
      float4 va = make_float4(0.f, 0.f, 0.f, 0.f), vb = va;
      if (m0 + r < N_NODES) {
        va = *(const float4*)&A[(size_t)(m0 + r) * IN_DIM + k0 + kc];
        vb = *(const float4*)&A[(size_t)(m0 + r) * IN_DIM + k0 + kc + 4];
      }
      uint4 p;
      p.x = packbf(va.x, va.y); p.y = packbf(va.z, va.w);
      p.z = packbf(vb.x, vb.y); p.w = packbf(vb.z, vb.w);
      *(uint4*)&As[r][kc] = p;
    }
    __syncthreads();
    bf16x8 a[4];
    #pragma unroll
    for (int rt = 0; rt < 4; ++rt) a[rt] = *(const bf16x8*)&As[rh + rt * 16 + lr][lk * 8];
    #pragma unroll
    for (int ct = 0; ct < 4; ++ct) {
      bf16x8 b = ((const bf16x8*)Bpk)[((hh * 4 + ct) * 4 + kk) * 64 + l];
      #pragma unroll
      for (int rt = 0; rt < 4; ++rt)
        acc[rt][ct] = __builtin_amdgcn_mfma_f32_16x16x32_bf16(a[rt], b, acc[rt][ct], 0, 0, 0);
    }
    __syncthreads();
  }
  float ala[4], ara[4];
  #pragma unroll
  for (int ct = 0; ct < 4; ++ct) {
    ala[ct] = al[hh * 64 + ct * 16 + lr];
    ara[ct] = ar[hh * 64 + ct * 16 + lr];
  }
  #pragma unroll
  for (int rt = 0; rt < 4; ++rt)
    #pragma unroll
    for (int j = 0; j < 4; ++j) {
      float pel = 0.f, per = 0.f;
      #pragma unroll
      for (int ct = 0; ct < 4; ++ct) {
        float v = acc[rt][ct][j];
        pel = fmaf(v, ala[ct], pel);
        per = fmaf(v, ara[ct], per);
      }
      #pragma unroll
      for (int o = 1; o <= 8; o <<= 1) {
        pel += __shfl_xor(pel, o);
        per += __shfl_xor(per, o);
      }
      int row = m0 + rh + rt * 16 + lk * 4 + j;
      if (lr == 0 && row < N_NODES) { el[row * 4 + hh] = pel; er[row * 4 + hh] = per; }
    }
  #pragma unroll
  for (int rt = 0; rt < 4; ++rt)
    #pragma unroll
    for (int ct = 0; ct < 4; ++ct)
      #pragma unroll
      for (int j = 0; j < 4; ++j) {
        int row = m0 + rh + rt * 16 + lk * 4 + j;
        if (row < N_NODES) C[(size_t)row * 256 + hh * 64 + ct * 16 + lr] = f2bf(acc[rt][ct][j]);
      }
}

// ==== k2: scan1 (49 blocks @ 512 thr) ====
__global__ __launch_bounds__(512) void k_scan(const int* __restrict__ cnt,
                                              int* __restrict__ offp,
                                              int* __restrict__ bsum) {
  __shared__ int lds[512];
  const int tid = threadIdx.x;
  int i = blockIdx.x * 1024 + tid * 2;
  int v0 = (i < N_NODES) ? cnt[i] : 0;
  int v1 = (i + 1 < N_NODES) ? cnt[i + 1] : 0;
  int t = v0 + v1;
  lds[tid] = t;
  __syncthreads();
  for (int s = 1; s < 512; s <<= 1) {
    int u = (tid >= s) ? lds[tid - s] : 0;
    __syncthreads();
    lds[tid] += u;
    __syncthreads();
  }
  int excl = lds[tid] - t;
  if (i < N_NODES) offp[i] = excl;
  if (i + 1 < N_NODES) offp[i + 1] = excl + v0;
  if (tid == 511) bsum[blockIdx.x] = lds[511];
}

// ==== k3: off-finalize (49 blk) + atomic-free place, 4 edges/thread (782) ====
__global__ __launch_bounds__(256) void k_place(const int* __restrict__ offp,
                                               const int* __restrict__ bsum,
                                               int* __restrict__ off,
                                               const int* __restrict__ src,
                                               const int* __restrict__ dst,
                                               const int* __restrict__ slot,
                                               int* __restrict__ ssrc) {
  __shared__ int pref[64];
  const int tid = threadIdx.x;
  const int bid = blockIdx.x;
  if (bid < 49) {
    if (tid < 64) {
      int v = (tid < bid) ? bsum[tid] : 0;
      #pragma unroll
      for (int o = 1; o < 64; o <<= 1) v += __shfl_xor(v, o);
      if (tid == 0) pref[0] = v;
    }
    __syncthreads();
    int e0 = pref[0];
    int i = bid * 1024 + tid * 4;
    if (i + 3 < N_NODES) {
      int4 q = *(const int4*)&offp[i];
      *(int4*)&off[i] = make_int4(q.x + e0, q.y + e0, q.z + e0, q.w + e0);
    } else {
      if (i < N_NODES) off[i] = offp[i] + e0;
      if (i + 1 < N_NODES) off[i + 1] = offp[i + 1] + e0;
      if (i + 2 < N_NODES) off[i + 2] = offp[i + 2] + e0;
      if (i + 3 < N_NODES) off[i + 3] = offp[i + 3] + e0;
    }
    if (bid == 0 && tid == 0) off[N_NODES] = N_EDGES;
    return;
  }
  if (tid < 64) {
    int v = (tid < 49) ? bsum[tid] : 0;
    int orig = v;
    #pragma unroll
    for (int o = 1; o < 64; o <<= 1) { int u = __shfl_up(v, o); if (tid >= o) v += u; }
    pref[tid] = v - orig;
  }
  __syncthreads();
  int e0 = (bid - 49) * 1024 + tid * 4;
  if (e0 < N_EDGES) {
    int4 d4 = *(const int4*)&dst[e0];
    int4 s4 = *(const int4*)&src[e0];
    int4 p4 = *(const int4*)&slot[e0];
    ssrc[offp[d4.x] + pref[d4.x >> 10] + p4.x] = s4.x;
    ssrc[offp[d4.y] + pref[d4.y >> 10] + p4.y] = s4.y;
    ssrc[offp[d4.z] + pref[d4.z >> 10] + p4.z] = s4.z;
    ssrc[offp[d4.w] + pref[d4.w >> 10] + p4.w] = s4.w;
  }
}

// ==== layer-1 agg, fused softmax ====
__global__ __launch_bounds__(256) void agg4f_k(const ushort_t* __restrict__ ftb,
                                               const float* __restrict__ el,
                                               const float* __restrict__ er,
                                               const int* __restrict__ off,
                                               const int* __restrict__ ssrc,
                                               const float* __restrict__ bias,
                                               ushort_t* __restrict__ outb) {
  __shared__ float wl[4][64][4];
  __shared__ int srcl[4][64];
  int wv = threadIdx.x >> 6, lane = threadIdx.x & 63;
  int n = blockIdx.x * 4 + wv;
  if (n >= N_NODES) return;
  int s0 = off[n], s1 = off[n + 1];
  int half = lane >> 5, sl = lane & 31;
  int head = sl >> 3;
  const float4* el4 = (const float4*)el;
  float4 erv = ((const float4*)er)[n];
  float4 sum = make_float4(0.f, 0.f, 0.f, 0.f);
  float acc[8] = {};
  for (int c = s0; c < s1; c += 64) {
    int e = c + lane;
    float4 ex = make_float4(0.f, 0.f, 0.f, 0.f);
    int s = 0;
    if (e < s1) {
      s = ssrc[e];
      float4 q = el4[s];
      ex.x = __expf(lrelu(q.x + erv.x));
      ex.y = __expf(lrelu(q.y + erv.y));
      ex.z = __expf(lrelu(q.z + erv.z));
      ex.w = __expf(lrelu(q.w + erv.w));
      sum.x += ex.x; sum.y += ex.y; sum.z += ex.z; sum.w += ex.w;
    }
    srcl[wv][lane] = s;
    *(float4*)&wl[wv][lane][0] = ex;
    int cend = (c + 64 < s1) ? c + 64 : s1;
    #pragma unroll 8
    for (int i = c; i < cend; i += 2) {
      int e2 = i + half;
      if (e2 < cend) {
        int idx = e2 - c;
        int ss = srcl[wv][idx];
        float w = wl[wv][idx][head];
        uint4 u = *(const uint4*)&ftb[ss * 256 + sl * 8];
        acc[0] = fmaf(w, bflo(u.x), acc[0]);
        acc[1] = fmaf(w, bfhi(u.x), acc[1]);
        acc[2] = fmaf(w, bflo(u.y), acc[2]);
        acc[3] = fmaf(w, bfhi(u.y), acc[3]);
        acc[4] = fmaf(w, bflo(u.z), acc[4]);
        acc[5] = fmaf(w, bfhi(u.z), acc[5]);
        acc[6] = fmaf(w, bflo(u.w), acc[6]);
        acc[7] = fmaf(w, bfhi(u.w), acc[7]);
      }
    }
  }
  #pragma unroll
  for (int o = 1; o <= 32; o <<= 1) {
    sum.x += __shfl_xor(sum.x, o); sum.y += __shfl_xor(sum.y, o);
    sum.z += __shfl_xor(sum.z, o); sum.w += __shfl_xor(sum.w, o);
  }
  #pragma unroll
  for (int j = 0; j < 8; ++j) acc[j] += __shfl_xor(acc[j], 32);
  if (half == 0) {
    float sd = (head == 0) ? sum.x : (head == 1) ? sum.y : (head == 2) ? sum.z : sum.w;
    float rsv = (s1 > s0) ? 1.f / sd : 0.f;
    float4 b0 = ((const float4*)bias)[sl * 2];
    float4 b1 = ((const float4*)bias)[sl * 2 + 1];
    float o[8] = {fmaf(acc[0], rsv, b0.x), fmaf(acc[1], rsv, b0.y),
                  fmaf(acc[2], rsv, b0.z), fmaf(acc[3], rsv, b0.w),
                  fmaf(acc[4], rsv, b1.x), fmaf(acc[5], rsv, b1.y),
                  fmaf(acc[6], rsv, b1.z), fmaf(acc[7], rsv, b1.w)};
    #pragma unroll
    for (int j = 0; j < 8; ++j) o[j] = (o[j] > 0.f) ? o[j] : expm1f(o[j]);
    uint4 p;
    p.x = packbf(o[0], o[1]); p.y = packbf(o[2], o[3]);
    p.z = packbf(o[4], o[5]); p.w = packbf(o[6], o[7]);
    *(uint4*)&outb[n * 256 + sl * 8] = p;
  }
}

// ==== layer-2 GEMM: 128x64 tile, 512 thr, pre-packed B, fused el/er ====
__global__ __launch_bounds__(512) void gemm2_mfma(const ushort_t* __restrict__ A,
                                                  const ushort_t* __restrict__ Bpk,
                                                  ushort_t* __restrict__ C,
                                                  const float* __restrict__ al,
                                                  const float* __restrict__ ar,
                                                  float* __restrict__ el,
                                                  float* __restrict__ er, int M) {
  __shared__ ushort_t As[128][40];
  const int tid = threadIdx.x;
  const int m0 = blockIdx.x * 128;
  const int w = tid >> 6, l = tid & 63;
  const int lr = l & 15, lk = l >> 4;
  f32x4 acc[4] = {};

  #pragma unroll
  for (int kk = 0; kk < 8; ++kk) {
    int k0 = kk * 32;
    {
      int r = tid >> 2, kc = (tid & 3) * 8;
      uint4 v = make_uint4(0, 0, 0, 0);
      if (m0 + r < M) v = *(const uint4*)&A[(size_t)(m0 + r) * 256 + k0 + kc];
      *(uint4*)&As[r][kc] = v;
    }
    __syncthreads();
    bf16x8 a = *(const bf16x8*)&As[w * 16 + lr][lk * 8];
    #pragma unroll
    for (int ct = 0; ct < 4; ++ct) {
      bf16x8 b = ((const bf16x8*)Bpk)[(ct * 8 + kk) * 64 + l];
      acc[ct] = __builtin_amdgcn_mfma_f32_16x16x32_bf16(a, b, acc[ct], 0, 0, 0);
    }
    __syncthreads();
  }
  float ala[4], ara[4];
  #pragma unroll
  for (int ct = 0; ct < 4; ++ct) {
    ala[ct] = al[ct * 16 + lr];
    ara[ct] = ar[ct * 16 + lr];
  }
  #pragma unroll
  for (int j = 0; j < 4; ++j) {
    float pel = 0.f, per = 0.f;
    #pragma unroll
    for (int ct = 0; ct < 4; ++ct) {
      float v = acc[ct][j];
      pel = fmaf(v, ala[ct], pel);
      per = fmaf(v, ara[ct], per);
    }
    #pragma unroll
    for (int o = 1; o <= 8; o <<= 1) {
      pel += __shfl_xor(pel, o);
      per += __shfl_xor(per, o);
    }
    int row = m0 + w * 16 + lk * 4 + j;
    if (lr == 0 && row < M) { el[row] = pel; er[row] = per; }
  }
  #pragma unroll
  for (int ct = 0; ct < 4; ++ct)
    #pragma unroll
    for (int j = 0; j < 4; ++j) {
      int row = m0 + w * 16 + lk * 4 + j;
      if (row < M) C[(size_t)row * 64 + ct * 16 + lr] = f2bf(acc[ct][j]);
    }
}

// ==== layer-2 agg, fused softmax ====
__global__ __launch_bounds__(256) void agg1f_k(const ushort_t* __restrict__ ftb,
                                               const float* __restrict__ el,
                                               const float* __restrict__ er,
                                               const int* __restrict__ off,
                                               const int* __restrict__ ssrc,
                                               const float* __restrict__ bias,
                                               float* __restrict__ out) {
  __shared__ float wl[4][64];
  __shared__ int srcl[4][64];
  int wv = threadIdx.x >> 6, lane = threadIdx.x & 63;
  int n = blockIdx.x * 4 + wv;
  if (n >= N_NODES) return;
  int s0 = off[n], s1 = off[n + 1];
  int g = lane >> 3, cg = lane & 7;
  float erv = er[n];
  float sum = 0.f;
  float acc[8] = {};
  for (int c = s0; c < s1; c += 64) {
    int e = c + lane;
    float ex = 0.f;
    int s = 0;
    if (e < s1) {
      s = ssrc[e];
      ex = __expf(lrelu(el[s] + erv));
      sum += ex;
    }
    srcl[wv][lane] = s;
    wl[wv][lane] = ex;
    int cend = (c + 64 < s1) ? c + 64 : s1;
    #pragma unroll 4
    for (int i = c; i < cend; i += 8) {
      int e2 = i + g;
      if (e2 < cend) {
        int idx = e2 - c;
        int ss = srcl[wv][idx];
        float w = wl[wv][idx];
        uint4 u = *(const uint4*)&ftb[ss * 64 + cg * 8];
        acc[0] = fmaf(w, bflo(u.x), acc[0]);
        acc[1] = fmaf(w, bfhi(u.x), acc[1]);
        acc[2] = fmaf(w, bflo(u.y), acc[2]);
        acc[3] = fmaf(w, bfhi(u.y), acc[3]);
        acc[4] = fmaf(w, bflo(u.z), acc[4]);
        acc[5] = fmaf(w, bfhi(u.z), acc[5]);
        acc[6] = fmaf(w, bflo(u.w), acc[6]);
        acc[7] = fmaf(w, bfhi(u.w), acc[7]);
      }
    }
  }
  #pragma unroll
  for (int o = 1; o <= 32; o <<= 1) sum += __shfl_xor(sum, o);
  #pragma unroll
  for (int o = 8; o <= 32; o <<= 1)
    #pragma unroll
    for (int j = 0; j < 8; ++j) acc[j] += __shfl_xor(acc[j], o);
  if (g == 0) {
    float rsv = (s1 > s0) ? 1.f / sum : 0.f;
    float4 b0 = ((const float4*)bias)[cg * 2];
    float4 b1 = ((const float4*)bias)[cg * 2 + 1];
    float o[8] = {fmaf(acc[0], rsv, b0.x), fmaf(acc[1], rsv, b0.y),
                  fmaf(acc[2], rsv, b0.z), fmaf(acc[3], rsv, b0.w),
                  fmaf(acc[4], rsv, b1.x), fmaf(acc[5], rsv, b1.y),
                  fmaf(acc[6], rsv, b1.z), fmaf(acc[7], rsv, b1.w)};
    #pragma unroll
    for (int j = 0; j < 8; ++j) o[j] = (o[j] > 0.f) ? o[j] : expm1f(o[j]);
    float4* out4 = (float4*)out;
    out4[(size_t)n * 16 + cg * 2]     = make_float4(o[0], o[1], o[2], o[3]);
    out4[(size_t)n * 16 + cg * 2 + 1] = make_float4(o[4], o[5], o[6], o[7]);
  }
}

extern "C" void kernel_launch(void* const* d_in, const int* in_sizes, int n_in,
                              void* d_out, int out_size, void* d_ws, size_t ws_size,
                              hipStream_t stream) {
  const float* x   = (const float*)d_in[0];
  const int*   src = (const int*)d_in[1];
  const int*   dst = (const int*)d_in[2];
  const float* W1  = (const float*)d_in[3];
  const float* al1 = (const float*)d_in[4];
  const float* ar1 = (const float*)d_in[5];
  const float* b1  = (const float*)d_in[6];
  const float* W2  = (const float*)d_in[7];
  const float* al2 = (const float*)d_in[8];
  const float* ar2 = (const float*)d_in[9];
  const float* b2  = (const float*)d_in[10];
  float* out = (float*)d_out;

  char* ws = (char*)d_ws;
  size_t wo = 0;
  auto alloc = [&](size_t b) { void* p = ws + wo; wo = (wo + b + 255) & ~(size_t)255; return p; };
  ushort_t* ft1b = (ushort_t*)alloc((size_t)N_NODES * 256 * 2);  // reused as ft2b
  ushort_t* h1b  = (ushort_t*)alloc((size_t)N_NODES * 256 * 2);
  ushort_t* bpk1 = (ushort_t*)alloc((size_t)IN_DIM * 256 * 2);
  ushort_t* bpk2 = (ushort_t*)alloc((size_t)256 * 64 * 2);
  float* el1 = (float*)alloc((size_t)N_NODES * 4 * 4);
  float* er1 = (float*)alloc((size_t)N_NODES * 4 * 4);
  int*   off = (int*)alloc((size_t)(N_NODES + 1) * 4);
  int*   offp= (int*)alloc((size_t)N_NODES * 4);
  int*   cnt = (int*)alloc((size_t)N_NODES * 4);
  int*   slot= (int*)alloc((size_t)N_EDGES * 4);
  int*   bsum= (int*)alloc(256);
  int*   ssrc= (int*)alloc((size_t)N_EDGES * 4);
  ushort_t* ft2b = ft1b;
  float* el2 = el1, *er2 = er1;

  k0_pack<<<12, 512, 0, stream>>>(W1, W2, bpk1, bpk2, cnt);
  // k1: gemm1 [0,391) | hist [391, 782)
  k_gemm1_hist<<<391 + 391, 512, 0, stream>>>(
      x, bpk1, ft1b, al1, ar1, el1, er1, dst, cnt, slot);
  k_scan<<<49, 512, 0, stream>>>(cnt, offp, bsum);
  k_place<<<49 + 782, 256, 0, stream>>>(offp, bsum, off, src, dst, slot, ssrc);
  agg4f_k<<<(N_NODES + 3) / 4, 256, 0, stream>>>(ft1b, el1, er1, off, ssrc, b1, h1b);
  gemm2_mfma<<<391, 512, 0, stream>>>(h1b, bpk2, ft2b, al2, ar2, el2, er2, N_NODES);
  agg1f_k<<<(N_NODES + 3) / 4, 256, 0, stream>>>(ft2b, el2, er2, off, ssrc, b2, out);
}

// Round 15
// 185.597 us; speedup vs baseline: 1.7893x; 1.0063x over previous
//
#include <hip/hip_runtime.h>
#include <hip/hip_bf16.h>
#include <math.h>

#define N_NODES 50000
#define N_EDGES 800000
#define IN_DIM 128
#define HID 64
#define HEADS 4

typedef unsigned short ushort_t;
typedef __attribute__((ext_vector_type(8))) short bf16x8;
typedef __attribute__((ext_vector_type(4))) float f32x4;

static __device__ __forceinline__ ushort_t f2bf(float f) {
  __hip_bfloat16 b = __float2bfloat16(f);
  return *(ushort_t*)&b;
}
static __device__ __forceinline__ float bflo(unsigned d) {
  union { unsigned u; float f; } c; c.u = d << 16; return c.f;
}
static __device__ __forceinline__ float bfhi(unsigned d) {
  union { unsigned u; float f; } c; c.u = d & 0xffff0000u; return c.f;
}
static __device__ __forceinline__ unsigned packbf(float lo, float hi) {
  return (unsigned)f2bf(lo) | ((unsigned)f2bf(hi) << 16);
}
static __device__ __forceinline__ float lrelu(float x) {
  return (x > 0.f) ? x : 0.01f * x;
}

// ==== k0: pack W1/W2 into MFMA B-frag layout + zero cnt (12 blk x 512) ====
__global__ __launch_bounds__(512) void k0_pack(const float* __restrict__ w1,
                                               const float* __restrict__ w2,
                                               ushort_t* __restrict__ bpk1,
                                               ushort_t* __restrict__ bpk2,
                                               int* __restrict__ cnt) {
  int t = blockIdx.x * 512 + threadIdx.x;
  for (int i = t; i < N_NODES; i += 12 * 512) cnt[i] = 0;
  if (t < 4096) {
    int l = t & 63, rem = t >> 6;
    int kk = rem & 3, ct = (rem >> 2) & 3, hh = rem >> 4;
    int kb = kk * 32 + (l >> 4) * 8;
    int col = hh * 64 + ct * 16 + (l & 15);
    ushort_t v[8];
    #pragma unroll
    for (int j = 0; j < 8; ++j) v[j] = f2bf(w1[(kb + j) * 256 + col]);
    *(uint4*)&bpk1[t * 8] = *(uint4*)v;
  } else if (t < 6144) {
    int u = t - 4096;
    int l = u & 63, rem = u >> 6;
    int kk = rem & 7, ct = rem >> 3;
    int kb = kk * 32 + (l >> 4) * 8;
    int col = ct * 16 + (l & 15);
    ushort_t v[8];
    #pragma unroll
    for (int j = 0; j < 8; ++j) v[j] = f2bf(w2[(kb + j) * 64 + col]);
    *(uint4*)&bpk2[u * 8] = *(uint4*)v;
  }
}

// ==== k1: gemm1 (391 blk) ∥ hist+slot 1 edge/thr (1563 blk) ====
__global__ __launch_bounds__(512) void k_gemm1_hist(
    const float* __restrict__ A, const ushort_t* __restrict__ Bpk,
    ushort_t* __restrict__ C, const float* __restrict__ al,
    const float* __restrict__ ar, float* __restrict__ el,
    float* __restrict__ er,
    const int* __restrict__ dst, int* __restrict__ cnt,
    int* __restrict__ slot) {
  __shared__ ushort_t As[128][40];
  const int tid = threadIdx.x;
  const int bid = blockIdx.x;
  if (bid >= 391) {
    // ---- hist: 1 edge/thread (max TLP to hide atomic latency) ----
    int e = (bid - 391) * 512 + tid;
    if (e < N_EDGES) {
      int d = dst[e];
      int p = atomicAdd(&cnt[d], 1);
      slot[e] = p;
    }
    return;
  }
  // ---- gemm1: tile 128 x 256, 8 waves (wave = head x row-half) ----
  const int m0 = bid * 128;
  const int w = tid >> 6, l = tid & 63;
  const int hh = w >> 1, rh = (w & 1) * 64;
  const int lr = l & 15, lk = l >> 4;
  f32x4 acc[4][4] = {};

  #pragma unroll
  for (int kk = 0; kk < 4; ++kk) {
    int k0 = kk * 32;
    {
      int r = tid >> 2, kc = (tid & 3) * 8;
      float4 va = make_float4(0.f, 0.f, 0.f, 0.f), vb = va;
      if (m0 + r < N_NODES) {
        va = *(const float4*)&A[(size_t)(m0 + r) * IN_DIM + k0 + kc];
        vb = *(const float4*)&A[(size_t)(m0 + r) * IN_DIM + k0 + kc + 4];
      }
      uint4 p;
      p.x = packbf(va.x, va.y); p.y = packbf(va.z, va.w);
      p.z = packbf(vb.x, vb.y); p.w = packbf(vb.z, vb.w);
      *(uint4*)&As[r][kc] = p;
    }
    __syncthreads();
    bf16x8 a[4];
    #pragma unroll
    for (int rt = 0; rt < 4; ++rt) a[rt] = *(const bf16x8*)&As[rh + rt * 16 + lr][lk * 8];
    #pragma unroll
    for (int ct = 0; ct < 4; ++ct) {
      bf16x8 b = ((const bf16x8*)Bpk)[((hh * 4 + ct) * 4 + kk) * 64 + l];
      #pragma unroll
      for (int rt = 0; rt < 4; ++rt)
        acc[rt][ct] = __builtin_amdgcn_mfma_f32_16x16x32_bf16(a[rt], b, acc[rt][ct], 0, 0, 0);
    }
    __syncthreads();
  }
  float ala[4], ara[4];
  #pragma unroll
  for (int ct = 0; ct < 4; ++ct) {
    ala[ct] = al[hh * 64 + ct * 16 + lr];
    ara[ct] = ar[hh * 64 + ct * 16 + lr];
  }
  #pragma unroll
  for (int rt = 0; rt < 4; ++rt)
    #pragma unroll
    for (int j = 0; j < 4; ++j) {
      float pel = 0.f, per = 0.f;
      #pragma unroll
      for (int ct = 0; ct < 4; ++ct) {
        float v = acc[rt][ct][j];
        pel = fmaf(v, ala[ct], pel);
        per = fmaf(v, ara[ct], per);
      }
      #pragma unroll
      for (int o = 1; o <= 8; o <<= 1) {
        pel += __shfl_xor(pel, o);
        per += __shfl_xor(per, o);
      }
      int row = m0 + rh + rt * 16 + lk * 4 + j;
      if (lr == 0 && row < N_NODES) { el[row * 4 + hh] = pel; er[row * 4 + hh] = per; }
    }
  #pragma unroll
  for (int rt = 0; rt < 4; ++rt)
    #pragma unroll
    for (int ct = 0; ct < 4; ++ct)
      #pragma unroll
      for (int j = 0; j < 4; ++j) {
        int row = m0 + rh + rt * 16 + lk * 4 + j;
        if (row < N_NODES) C[(size_t)row * 256 + hh * 64 + ct * 16 + lr] = f2bf(acc[rt][ct][j]);
      }
}

// ==== k2: scan1 (49 blocks @ 512 thr) ====
__global__ __launch_bounds__(512) void k_scan(const int* __restrict__ cnt,
                                              int* __restrict__ offp,
                                              int* __restrict__ bsum) {
  __shared__ int lds[512];
  const int tid = threadIdx.x;
  int i = blockIdx.x * 1024 + tid * 2;
  int v0 = (i < N_NODES) ? cnt[i] : 0;
  int v1 = (i + 1 < N_NODES) ? cnt[i + 1] : 0;
  int t = v0 + v1;
  lds[tid] = t;
  __syncthreads();
  for (int s = 1; s < 512; s <<= 1) {
    int u = (tid >= s) ? lds[tid - s] : 0;
    __syncthreads();
    lds[tid] += u;
    __syncthreads();
  }
  int excl = lds[tid] - t;
  if (i < N_NODES) offp[i] = excl;
  if (i + 1 < N_NODES) offp[i + 1] = excl + v0;
  if (tid == 511) bsum[blockIdx.x] = lds[511];
}

// ==== k3: off-finalize (49 blk) + atomic-free place, 4 edges/thread (782) ====
__global__ __launch_bounds__(256) void k_place(const int* __restrict__ offp,
                                               const int* __restrict__ bsum,
                                               int* __restrict__ off,
                                               const int* __restrict__ src,
                                               const int* __restrict__ dst,
                                               const int* __restrict__ slot,
                                               int* __restrict__ ssrc) {
  __shared__ int pref[64];
  const int tid = threadIdx.x;
  const int bid = blockIdx.x;
  if (bid < 49) {
    if (tid < 64) {
      int v = (tid < bid) ? bsum[tid] : 0;
      #pragma unroll
      for (int o = 1; o < 64; o <<= 1) v += __shfl_xor(v, o);
      if (tid == 0) pref[0] = v;
    }
    __syncthreads();
    int e0 = pref[0];
    int i = bid * 1024 + tid * 4;
    if (i + 3 < N_NODES) {
      int4 q = *(const int4*)&offp[i];
      *(int4*)&off[i] = make_int4(q.x + e0, q.y + e0, q.z + e0, q.w + e0);
    } else {
      if (i < N_NODES) off[i] = offp[i] + e0;
      if (i + 1 < N_NODES) off[i + 1] = offp[i + 1] + e0;
      if (i + 2 < N_NODES) off[i + 2] = offp[i + 2] + e0;
      if (i + 3 < N_NODES) off[i + 3] = offp[i + 3] + e0;
    }
    if (bid == 0 && tid == 0) off[N_NODES] = N_EDGES;
    return;
  }
  if (tid < 64) {
    int v = (tid < 49) ? bsum[tid] : 0;
    int orig = v;
    #pragma unroll
    for (int o = 1; o < 64; o <<= 1) { int u = __shfl_up(v, o); if (tid >= o) v += u; }
    pref[tid] = v - orig;
  }
  __syncthreads();
  int e0 = (bid - 49) * 1024 + tid * 4;
  if (e0 < N_EDGES) {
    int4 d4 = *(const int4*)&dst[e0];
    int4 s4 = *(const int4*)&src[e0];
    int4 p4 = *(const int4*)&slot[e0];
    ssrc[offp[d4.x] + pref[d4.x >> 10] + p4.x] = s4.x;
    ssrc[offp[d4.y] + pref[d4.y >> 10] + p4.y] = s4.y;
    ssrc[offp[d4.z] + pref[d4.z >> 10] + p4.z] = s4.z;
    ssrc[offp[d4.w] + pref[d4.w >> 10] + p4.w] = s4.w;
  }
}

// ==== layer-1 agg, fused softmax ====
__global__ __launch_bounds__(256) void agg4f_k(const ushort_t* __restrict__ ftb,
                                               const float* __restrict__ el,
                                               const float* __restrict__ er,
                                               const int* __restrict__ off,
                                               const int* __restrict__ ssrc,
                                               const float* __restrict__ bias,
                                               ushort_t* __restrict__ outb) {
  __shared__ float wl[4][64][4];
  __shared__ int srcl[4][64];
  int wv = threadIdx.x >> 6, lane = threadIdx.x & 63;
  int n = blockIdx.x * 4 + wv;
  if (n >= N_NODES) return;
  int s0 = off[n], s1 = off[n + 1];
  int half = lane >> 5, sl = lane & 31;
  int head = sl >> 3;
  const float4* el4 = (const float4*)el;
  float4 erv = ((const float4*)er)[n];
  float4 sum = make_float4(0.f, 0.f, 0.f, 0.f);
  float acc[8] = {};
  for (int c = s0; c < s1; c += 64) {
    int e = c + lane;
    float4 ex = make_float4(0.f, 0.f, 0.f, 0.f);
    int s = 0;
    if (e < s1) {
      s = ssrc[e];
      float4 q = el4[s];
      ex.x = __expf(lrelu(q.x + erv.x));
      ex.y = __expf(lrelu(q.y + erv.y));
      ex.z = __expf(lrelu(q.z + erv.z));
      ex.w = __expf(lrelu(q.w + erv.w));
      sum.x += ex.x; sum.y += ex.y; sum.z += ex.z; sum.w += ex.w;
    }
    srcl[wv][lane] = s;
    *(float4*)&wl[wv][lane][0] = ex;
    int cend = (c + 64 < s1) ? c + 64 : s1;
    #pragma unroll 8
    for (int i = c; i < cend; i += 2) {
      int e2 = i + half;
      if (e2 < cend) {
        int idx = e2 - c;
        int ss = srcl[wv][idx];
        float w = wl[wv][idx][head];
        uint4 u = *(const uint4*)&ftb[ss * 256 + sl * 8];
        acc[0] = fmaf(w, bflo(u.x), acc[0]);
        acc[1] = fmaf(w, bfhi(u.x), acc[1]);
        acc[2] = fmaf(w, bflo(u.y), acc[2]);
        acc[3] = fmaf(w, bfhi(u.y), acc[3]);
        acc[4] = fmaf(w, bflo(u.z), acc[4]);
        acc[5] = fmaf(w, bfhi(u.z), acc[5]);
        acc[6] = fmaf(w, bflo(u.w), acc[6]);
        acc[7] = fmaf(w, bfhi(u.w), acc[7]);
      }
    }
  }
  #pragma unroll
  for (int o = 1; o <= 32; o <<= 1) {
    sum.x += __shfl_xor(sum.x, o); sum.y += __shfl_xor(sum.y, o);
    sum.z += __shfl_xor(sum.z, o); sum.w += __shfl_xor(sum.w, o);
  }
  #pragma unroll
  for (int j = 0; j < 8; ++j) acc[j] += __shfl_xor(acc[j], 32);
  if (half == 0) {
    float sd = (head == 0) ? sum.x : (head == 1) ? sum.y : (head == 2) ? sum.z : sum.w;
    float rsv = (s1 > s0) ? 1.f / sd : 0.f;
    float4 b0 = ((const float4*)bias)[sl * 2];
    float4 b1 = ((const float4*)bias)[sl * 2 + 1];
    float o[8] = {fmaf(acc[0], rsv, b0.x), fmaf(acc[1], rsv, b0.y),
                  fmaf(acc[2], rsv, b0.z), fmaf(acc[3], rsv, b0.w),
                  fmaf(acc[4], rsv, b1.x), fmaf(acc[5], rsv, b1.y),
                  fmaf(acc[6], rsv, b1.z), fmaf(acc[7], rsv, b1.w)};
    #pragma unroll
    for (int j = 0; j < 8; ++j) o[j] = (o[j] > 0.f) ? o[j] : expm1f(o[j]);
    uint4 p;
    p.x = packbf(o[0], o[1]); p.y = packbf(o[2], o[3]);
    p.z = packbf(o[4], o[5]); p.w = packbf(o[6], o[7]);
    *(uint4*)&outb[n * 256 + sl * 8] = p;
  }
}

// ==== layer-2 GEMM: 128x64 tile, 512 thr, pre-packed B, fused el/er ====
__global__ __launch_bounds__(512) void gemm2_mfma(const ushort_t* __restrict__ A,
                                                  const ushort_t* __restrict__ Bpk,
                                                  ushort_t* __restrict__ C,
                                                  const float* __restrict__ al,
                                                  const float* __restrict__ ar,
                                                  float* __restrict__ el,
                                                  float* __restrict__ er, int M) {
  __shared__ ushort_t As[128][40];
  const int tid = threadIdx.x;
  const int m0 = blockIdx.x * 128;
  const int w = tid >> 6, l = tid & 63;
  const int lr = l & 15, lk = l >> 4;
  f32x4 acc[4] = {};

  #pragma unroll
  for (int kk = 0; kk < 8; ++kk) {
    int k0 = kk * 32;
    {
      int r = tid >> 2, kc = (tid & 3) * 8;
      uint4 v = make_uint4(0, 0, 0, 0);
      if (m0 + r < M) v = *(const uint4*)&A[(size_t)(m0 + r) * 256 + k0 + kc];
      *(uint4*)&As[r][kc] = v;
    }
    __syncthreads();
    bf16x8 a = *(const bf16x8*)&As[w * 16 + lr][lk * 8];
    #pragma unroll
    for (int ct = 0; ct < 4; ++ct) {
      bf16x8 b = ((const bf16x8*)Bpk)[(ct * 8 + kk) * 64 + l];
      acc[ct] = __builtin_amdgcn_mfma_f32_16x16x32_bf16(a, b, acc[ct], 0, 0, 0);
    }
    __syncthreads();
  }
  float ala[4], ara[4];
  #pragma unroll
  for (int ct = 0; ct < 4; ++ct) {
    ala[ct] = al[ct * 16 + lr];
    ara[ct] = ar[ct * 16 + lr];
  }
  #pragma unroll
  for (int j = 0; j < 4; ++j) {
    float pel = 0.f, per = 0.f;
    #pragma unroll
    for (int ct = 0; ct < 4; ++ct) {
      float v = acc[ct][j];
      pel = fmaf(v, ala[ct], pel);
      per = fmaf(v, ara[ct], per);
    }
    #pragma unroll
    for (int o = 1; o <= 8; o <<= 1) {
      pel += __shfl_xor(pel, o);
      per += __shfl_xor(per, o);
    }
    int row = m0 + w * 16 + lk * 4 + j;
    if (lr == 0 && row < M) { el[row] = pel; er[row] = per; }
  }
  #pragma unroll
  for (int ct = 0; ct < 4; ++ct)
    #pragma unroll
    for (int j = 0; j < 4; ++j) {
      int row = m0 + w * 16 + lk * 4 + j;
      if (row < M) C[(size_t)row * 64 + ct * 16 + lr] = f2bf(acc[ct][j]);
    }
}

// ==== layer-2 agg, fused softmax ====
__global__ __launch_bounds__(256) void agg1f_k(const ushort_t* __restrict__ ftb,
                                               const float* __restrict__ el,
                                               const float* __restrict__ er,
                                               const int* __restrict__ off,
                                               const int* __restrict__ ssrc,
                                               const float* __restrict__ bias,
                                               float* __restrict__ out) {
  __shared__ float wl[4][64];
  __shared__ int srcl[4][64];
  int wv = threadIdx.x >> 6, lane = threadIdx.x & 63;
  int n = blockIdx.x * 4 + wv;
  if (n >= N_NODES) return;
  int s0 = off[n], s1 = off[n + 1];
  int g = lane >> 3, cg = lane & 7;
  float erv = er[n];
  float sum = 0.f;
  float acc[8] = {};
  for (int c = s0; c < s1; c += 64) {
    int e = c + lane;
    float ex = 0.f;
    int s = 0;
    if (e < s1) {
      s = ssrc[e];
      ex = __expf(lrelu(el[s] + erv));
      sum += ex;
    }
    srcl[wv][lane] = s;
    wl[wv][lane] = ex;
    int cend = (c + 64 < s1) ? c + 64 : s1;
    #pragma unroll 4
    for (int i = c; i < cend; i += 8) {
      int e2 = i + g;
      if (e2 < cend) {
        int idx = e2 - c;
        int ss = srcl[wv][idx];
        float w = wl[wv][idx];
        uint4 u = *(const uint4*)&ftb[ss * 64 + cg * 8];
        acc[0] = fmaf(w, bflo(u.x), acc[0]);
        acc[1] = fmaf(w, bfhi(u.x), acc[1]);
        acc[2] = fmaf(w, bflo(u.y), acc[2]);
        acc[3] = fmaf(w, bfhi(u.y), acc[3]);
        acc[4] = fmaf(w, bflo(u.z), acc[4]);
        acc[5] = fmaf(w, bfhi(u.z), acc[5]);
        acc[6] = fmaf(w, bflo(u.w), acc[6]);
        acc[7] = fmaf(w, bfhi(u.w), acc[7]);
      }
    }
  }
  #pragma unroll
  for (int o = 1; o <= 32; o <<= 1) sum += __shfl_xor(sum, o);
  #pragma unroll
  for (int o = 8; o <= 32; o <<= 1)
    #pragma unroll
    for (int j = 0; j < 8; ++j) acc[j] += __shfl_xor(acc[j], o);
  if (g == 0) {
    float rsv = (s1 > s0) ? 1.f / sum : 0.f;
    float4 b0 = ((const float4*)bias)[cg * 2];
    float4 b1 = ((const float4*)bias)[cg * 2 + 1];
    float o[8] = {fmaf(acc[0], rsv, b0.x), fmaf(acc[1], rsv, b0.y),
                  fmaf(acc[2], rsv, b0.z), fmaf(acc[3], rsv, b0.w),
                  fmaf(acc[4], rsv, b1.x), fmaf(acc[5], rsv, b1.y),
                  fmaf(acc[6], rsv, b1.z), fmaf(acc[7], rsv, b1.w)};
    #pragma unroll
    for (int j = 0; j < 8; ++j) o[j] = (o[j] > 0.f) ? o[j] : expm1f(o[j]);
    float4* out4 = (float4*)out;
    out4[(size_t)n * 16 + cg * 2]     = make_float4(o[0], o[1], o[2], o[3]);
    out4[(size_t)n * 16 + cg * 2 + 1] = make_float4(o[4], o[5], o[6], o[7]);
  }
}

extern "C" void kernel_launch(void* const* d_in, const int* in_sizes, int n_in,
                              void* d_out, int out_size, void* d_ws, size_t ws_size,
                              hipStream_t stream) {
  const float* x   = (const float*)d_in[0];
  const int*   src = (const int*)d_in[1];
  const int*   dst = (const int*)d_in[2];
  const float* W1  = (const float*)d_in[3];
  const float* al1 = (const float*)d_in[4];
  const float* ar1 = (const float*)d_in[5];
  const float* b1  = (const float*)d_in[6];
  const float* W2  = (const float*)d_in[7];
  const float* al2 = (const float*)d_in[8];
  const float* ar2 = (const float*)d_in[9];
  const float* b2  = (const float*)d_in[10];
  float* out = (float*)d_out;

  char* ws = (char*)d_ws;
  size_t wo = 0;
  auto alloc = [&](size_t b) { void* p = ws + wo; wo = (wo + b + 255) & ~(size_t)255; return p; };
  ushort_t* ft1b = (ushort_t*)alloc((size_t)N_NODES * 256 * 2);  // reused as ft2b
  ushort_t* h1b  = (ushort_t*)alloc((size_t)N_NODES * 256 * 2);
  ushort_t* bpk1 = (ushort_t*)alloc((size_t)IN_DIM * 256 * 2);
  ushort_t* bpk2 = (ushort_t*)alloc((size_t)256 * 64 * 2);
  float* el1 = (float*)alloc((size_t)N_NODES * 4 * 4);
  float* er1 = (float*)alloc((size_t)N_NODES * 4 * 4);
  int*   off = (int*)alloc((size_t)(N_NODES + 1) * 4);
  int*   offp= (int*)alloc((size_t)N_NODES * 4);
  int*   cnt = (int*)alloc((size_t)N_NODES * 4);
  int*   slot= (int*)alloc((size_t)N_EDGES * 4);
  int*   bsum= (int*)alloc(256);
  int*   ssrc= (int*)alloc((size_t)N_EDGES * 4);
  ushort_t* ft2b = ft1b;
  float* el2 = el1, *er2 = er1;

  k0_pack<<<12, 512, 0, stream>>>(W1, W2, bpk1, bpk2, cnt);
  // k1: gemm1 [0,391) | hist [391, 391+1563)
  k_gemm1_hist<<<391 + 1563, 512, 0, stream>>>(
      x, bpk1, ft1b, al1, ar1, el1, er1, dst, cnt, slot);
  k_scan<<<49, 512, 0, stream>>>(cnt, offp, bsum);
  k_place<<<49 + 782, 256, 0, stream>>>(offp, bsum, off, src, dst, slot, ssrc);
  agg4f_k<<<(N_NODES + 3) / 4, 256, 0, stream>>>(ft1b, el1, er1, off, ssrc, b1, h1b);
  gemm2_mfma<<<391, 512, 0, stream>>>(h1b, bpk2, ft2b, al2, ar2, el2, er2, N_NODES);
  agg1f_k<<<(N_NODES + 3) / 4, 256, 0, stream>>>(ft2b, el2, er2, off, ssrc, b2, out);
}